// Round 2
// baseline (3345.299 us; speedup 1.0000x reference)
//
#include <hip/hip_runtime.h>

#define K_CODES 1024
#define D_DIM   256
#define N_VEC   32768
#define BETA    0.25f
#define DECAY   0.99f
#define EPSV    1e-5f

// d_out layout (float32), offsets in elements
#define OFF_ZQ   0
#define OFF_IDX  8388608
#define OFF_LOSS 8421376
#define OFF_EMB  8421377
#define OFF_CS   8683521
#define OFF_EMAW 8684545

#define BM  32    // n-vectors per block
#define NDT 64    // 256 d / 4 per chunk

// ws layout: embT[256][1024] at 0, enorm[1024] at 262144
#define WS_ENORM 262144

// ---------------------------------------------------------------- init
__global__ void k_init(float* __restrict__ out) {
    int i = blockIdx.x * 256 + threadIdx.x;   // 1024*256 = 262144
    if (i == 0) out[OFF_LOSS] = 0.f;
    if (i < K_CODES) out[OFF_CS + i] = 0.f;
    out[OFF_EMAW + i] = 0.f;
}

// ---------------------------------------------------------------- embT + ||e||^2
__global__ void k_prep(const float* __restrict__ emb, float* __restrict__ ws) {
    int j    = blockIdx.x * 4 + (threadIdx.x >> 6);   // 256 blocks, wave per row
    int lane = threadIdx.x & 63;
    float4 v = reinterpret_cast<const float4*>(emb + j * D_DIM)[lane];
    ws[(lane * 4 + 0) * 1024 + j] = v.x;
    ws[(lane * 4 + 1) * 1024 + j] = v.y;
    ws[(lane * 4 + 2) * 1024 + j] = v.z;
    ws[(lane * 4 + 3) * 1024 + j] = v.w;
    float s = v.x * v.x + v.y * v.y + v.z * v.z + v.w * v.w;
    #pragma unroll
    for (int o = 32; o > 0; o >>= 1) s += __shfl_xor(s, o, 64);
    if (lane == 0) ws[WS_ENORM + j] = s;
}

// ---------------------------------------------------------------- main
__global__ __launch_bounds__(512, 4)
void k_main(const float* __restrict__ z, const float* __restrict__ emb,
            const float* __restrict__ ws, float* __restrict__ out) {
    __shared__ float ztr[BM][260];          // [n][d], row 1040B (16B-aligned)
    __shared__ float etv[2][1024 * 4];      // dbuf: float4 per code, lane-consec
    __shared__ float znorm_s[BM];
    __shared__ float psum[BM][17];
    __shared__ float wred_d[8][BM];
    __shared__ int   wred_j[8][BM];
    __shared__ int   js_s[BM];
    __shared__ float dmin_s[BM];

    const int tid  = threadIdx.x;           // 0..511
    const int lane = tid & 63;
    const int w    = tid >> 6;              // 0..7: j-eighth
    const int n0   = blockIdx.x * BM;       // 1024 blocks
    const int b    = n0 >> 10;
    const int hw0  = n0 & 1023;
    const float* zb   = z + b * (D_DIM * 1024) + hw0;
    const float* embT = ws;

    // ---- stage z tile (coalesced float4 along n) into ztr[n][d]
    #pragma unroll
    for (int rep = 0; rep < 4; ++rep) {
        int flat = rep * 512 + tid;         // 0..2047
        int d    = flat >> 3;
        int n4   = (flat & 7) * 4;
        float4 v = *reinterpret_cast<const float4*>(zb + d * 1024 + n4);
        ztr[n4 + 0][d] = v.x; ztr[n4 + 1][d] = v.y;
        ztr[n4 + 2][d] = v.z; ztr[n4 + 3][d] = v.w;
    }
    // ---- stage etv chunk 0 (coalesced reads from embT, conflict-free b128 write)
    #pragma unroll
    for (int s = 0; s < 2; ++s) {
        int j = s * 512 + tid;
        float4 v;
        v.x = embT[0 * 1024 + j]; v.y = embT[1 * 1024 + j];
        v.z = embT[2 * 1024 + j]; v.w = embT[3 * 1024 + j];
        *reinterpret_cast<float4*>(&etv[0][j * 4]) = v;
    }
    __syncthreads();

    // ---- ||z||^2 partials
    {
        int nn = tid >> 4, seg = tid & 15;
        float s = 0.f;
        #pragma unroll
        for (int k = 0; k < 16; ++k) {
            float v = ztr[nn][seg * 16 + k];
            s += v * v;
        }
        psum[nn][seg] = s;
    }
    __syncthreads();
    if (tid < BM) {
        float s = 0.f;
        #pragma unroll
        for (int seg = 0; seg < 16; ++seg) s += psum[tid][seg];
        znorm_s[tid] = s;   // consumed after main loop (many barriers between)
    }

    // enorm for this thread's two codes, in registers
    const int j0 = w * 128 + lane;
    const int j1 = j0 + 64;
    const float en0 = ws[WS_ENORM + j0];
    const float en1 = ws[WS_ENORM + j1];

    float acc[BM][2];
    #pragma unroll
    for (int nn = 0; nn < BM; ++nn) { acc[nn][0] = 0.f; acc[nn][1] = 0.f; }

    // ---- main loop over 64 d-chunks of 4
    for (int dt = 0; dt < NDT; ++dt) {
        int c = dt & 1;
        if (dt + 1 < NDT) {                  // stage next chunk into other buffer
            const float* src = embT + (dt + 1) * 4 * 1024;
            #pragma unroll
            for (int s = 0; s < 2; ++s) {
                int j = s * 512 + tid;
                float4 v;
                v.x = src[j]; v.y = src[1024 + j];
                v.z = src[2048 + j]; v.w = src[3072 + j];
                *reinterpret_cast<float4*>(&etv[c ^ 1][j * 4]) = v;
            }
        }
        float4 e0 = *reinterpret_cast<float4*>(&etv[c][j0 * 4]);  // lane-consec: no conflict
        float4 e1 = *reinterpret_cast<float4*>(&etv[c][j1 * 4]);
        #pragma unroll
        for (int nn = 0; nn < BM; ++nn) {
            float4 zv = *reinterpret_cast<float4*>(&ztr[nn][dt * 4]);  // uniform: broadcast
            acc[nn][0] += zv.x * e0.x + zv.y * e0.y + zv.z * e0.z + zv.w * e0.w;
            acc[nn][1] += zv.x * e1.x + zv.y * e1.y + zv.z * e1.z + zv.w * e1.w;
        }
        __syncthreads();
    }

    // ---- distances + hierarchical argmin (tie -> smaller j, as np.argmin)
    #pragma unroll
    for (int nn = 0; nn < BM; ++nn) {
        float zn = znorm_s[nn];
        float d0 = zn + en0 - 2.f * acc[nn][0];
        float d1 = zn + en1 - 2.f * acc[nn][1];
        float best; int bj;
        if (d1 < d0) { best = d1; bj = j1; } else { best = d0; bj = j0; }
        #pragma unroll
        for (int o = 1; o < 64; o <<= 1) {
            float ov = __shfl_xor(best, o, 64);
            int   oj = __shfl_xor(bj, o, 64);
            if (ov < best || (ov == best && oj < bj)) { best = ov; bj = oj; }
        }
        if (lane == 0) { wred_d[w][nn] = best; wred_j[w][nn] = bj; }
    }
    __syncthreads();
    if (tid < BM) {
        int nn = tid;
        float best = wred_d[0][nn]; int bj = wred_j[0][nn];
        #pragma unroll
        for (int ww = 1; ww < 8; ++ww) {
            float dv = wred_d[ww][nn]; int jv = wred_j[ww][nn];
            if (dv < best || (dv == best && jv < bj)) { best = dv; bj = jv; }
        }
        out[OFF_IDX + n0 + nn] = (float)bj;
        js_s[nn]  = bj;
        dmin_s[nn] = best;
        atomicAdd(out + OFF_CS + bj, 1.0f);
    }
    __syncthreads();
    if (tid == 0) {
        float s = 0.f;
        #pragma unroll
        for (int nn = 0; nn < BM; ++nn) s += dmin_s[nn];
        atomicAdd(out + OFF_LOSS, s);        // sum d_min == sum ||z_q - z||^2
    }

    // ---- gather z_q (coalesced along n) + dw atomics
    #pragma unroll
    for (int rep = 0; rep < 16; ++rep) {
        int elem = rep * 512 + tid;          // 0..8191
        int d    = elem >> 5;
        int nn   = elem & 31;
        int j    = js_s[nn];
        out[OFF_ZQ + b * (D_DIM * 1024) + d * 1024 + hw0 + nn] = emb[j * D_DIM + d];
        atomicAdd(out + OFF_EMAW + j * D_DIM + d, ztr[nn][d]);
    }
}

// ---------------------------------------------------------------- cluster size + loss
__global__ void k_cs(const float* __restrict__ ema_cs, float* __restrict__ out) {
    __shared__ float red[K_CODES];
    int j = threadIdx.x;                     // 1024 threads
    float raw = ema_cs[j] * DECAY + (1.f - DECAY) * out[OFF_CS + j];
    red[j] = raw;
    __syncthreads();
    for (int s = 512; s > 0; s >>= 1) {
        if (j < s) red[j] += red[j + s];
        __syncthreads();
    }
    float ntot = red[0];
    float cs = (raw + EPSV) / (ntot + K_CODES * EPSV) * ntot;
    out[OFF_CS + j] = cs;
    if (j == 0) out[OFF_LOSS] = BETA * out[OFF_LOSS] / (float)(N_VEC * D_DIM);
}

// ---------------------------------------------------------------- embedding update
__global__ void k_emb(const float* __restrict__ ema_w, float* __restrict__ out) {
    int i = blockIdx.x * 256 + threadIdx.x;  // 1024 blocks -> 262144
    int j = i >> 8;
    float dw = out[OFF_EMAW + i];
    float nw = ema_w[i] * DECAY + (1.f - DECAY) * dw;
    out[OFF_EMAW + i] = nw;
    out[OFF_EMB + i]  = nw / out[OFF_CS + j];
}

// ---------------------------------------------------------------- launch
extern "C" void kernel_launch(void* const* d_in, const int* in_sizes, int n_in,
                              void* d_out, int out_size, void* d_ws, size_t ws_size,
                              hipStream_t stream) {
    const float* z      = (const float*)d_in[0];
    const float* emb    = (const float*)d_in[1];
    const float* ema_cs = (const float*)d_in[2];
    const float* ema_w  = (const float*)d_in[3];
    float* out = (float*)d_out;
    float* ws  = (float*)d_ws;               // needs ~1.03 MB

    hipLaunchKernelGGL(k_init, dim3(1024), dim3(256), 0, stream, out);
    hipLaunchKernelGGL(k_prep, dim3(256),  dim3(256), 0, stream, emb, ws);
    hipLaunchKernelGGL(k_main, dim3(N_VEC / BM), dim3(512), 0, stream, z, emb, ws, out);
    hipLaunchKernelGGL(k_cs,   dim3(1),    dim3(1024), 0, stream, ema_cs, out);
    hipLaunchKernelGGL(k_emb,  dim3(1024), dim3(256), 0, stream, ema_w, out);
}

// Round 3
// 1867.690 us; speedup vs baseline: 1.7911x; 1.7911x over previous
//
#include <hip/hip_runtime.h>

#define K_CODES 1024
#define D_DIM   256
#define N_VEC   32768
#define BETA    0.25f
#define DECAY   0.99f
#define EPSV    1e-5f

// d_out layout (float32), offsets in elements
#define OFF_ZQ   0
#define OFF_IDX  8388608
#define OFF_LOSS 8421376
#define OFF_EMB  8421377
#define OFF_CS   8683521
#define OFF_EMAW 8684545

// ws layout (floats): embT[256][1024] | enorm[1024] | sum_znorm
#define WS_ENORM 262144
#define WS_SZN   263168

#define BM 64     // n per block
#define NJ 128    // j per outer chunk
#define MR 8      // n per thread
#define NR 4      // j per thread

// ---------------------------------------------------------------- init
__global__ void k_init(float* __restrict__ out, float* __restrict__ ws) {
    int i = blockIdx.x * 256 + threadIdx.x;   // 1024*256 = 262144
    if (i == 0) { out[OFF_LOSS] = 0.f; ws[WS_SZN] = 0.f; }
    if (i < K_CODES) out[OFF_CS + i] = 0.f;
    out[OFF_EMAW + i] = 0.f;
}

// ---------------------------------------------------------------- embT + ||e||^2
__global__ void k_prep(const float* __restrict__ emb, float* __restrict__ ws) {
    int j    = blockIdx.x * 4 + (threadIdx.x >> 6);   // 256 blocks, wave per row
    int lane = threadIdx.x & 63;
    float4 v = reinterpret_cast<const float4*>(emb + j * D_DIM)[lane];
    ws[(lane * 4 + 0) * 1024 + j] = v.x;
    ws[(lane * 4 + 1) * 1024 + j] = v.y;
    ws[(lane * 4 + 2) * 1024 + j] = v.z;
    ws[(lane * 4 + 3) * 1024 + j] = v.w;
    float s = v.x * v.x + v.y * v.y + v.z * v.z + v.w * v.w;
    #pragma unroll
    for (int o = 32; o > 0; o >>= 1) s += __shfl_xor(s, o, 64);
    if (lane == 0) ws[WS_ENORM + j] = s;
}

// ---------------------------------------------------------------- sum ||z||^2
__global__ void k_zn(const float* __restrict__ z, float* __restrict__ ws) {
    int i = blockIdx.x * 256 + threadIdx.x;   // 8192 blocks -> 2.1M float4
    float4 v = reinterpret_cast<const float4*>(z)[i];
    float s = v.x * v.x + v.y * v.y + v.z * v.z + v.w * v.w;
    #pragma unroll
    for (int o = 32; o > 0; o >>= 1) s += __shfl_xor(s, o, 64);
    if ((threadIdx.x & 63) == 0) atomicAdd(ws + WS_SZN, s);
}

// ---------------------------------------------------------------- main
__global__ __launch_bounds__(256, 2)
void k_main(const float* __restrict__ z, const float* __restrict__ emb,
            const float* __restrict__ ws, float* __restrict__ out) {
    __shared__ float zt[2][4][BM];    // [buf][d_local][n]  2 KB
    __shared__ float el[2][4][NJ];    // [buf][d_local][j]  4 KB
    __shared__ int   js_s[BM];

    const int tid = threadIdx.x;      // 256 threads
    const int tx  = tid & 31;         // j-group
    const int ty  = tid >> 5;         // n-group (0..7)
    const int n0  = blockIdx.x * BM;  // 512 blocks
    const int b   = n0 >> 10;
    const int hw0 = n0 & 1023;
    const float* zb   = z + b * (D_DIM * 1024) + hw0;
    const float* embT = ws;

    const int sdl = tid >> 6, snl = tid & 63;   // z staging coords

    float best[MR]; int bj[MR];
    #pragma unroll
    for (int m = 0; m < MR; ++m) { best[m] = 3.4e38f; bj[m] = 0; }

    // stage (jc=0, dt=0) into buf 0
    zt[0][sdl][snl] = zb[sdl * 1024 + snl];
    #pragma unroll
    for (int s = 0; s < 2; ++s) {
        int idx = s * 256 + tid;
        int dle = idx >> 7, jl = idx & 127;
        el[0][dle][jl] = embT[dle * 1024 + jl];
    }
    __syncthreads();

    float lsum = 0.f;

    for (int jc = 0; jc < 8; ++jc) {
        float acc[MR][NR];
        #pragma unroll
        for (int m = 0; m < MR; ++m)
            #pragma unroll
            for (int q = 0; q < NR; ++q) acc[m][q] = 0.f;

        for (int dt = 0; dt < 64; ++dt) {
            int buf = dt & 1;
            // prefetch next chunk into other buffer
            if (dt < 63 || jc < 7) {
                int njc = (dt < 63) ? jc : jc + 1;
                int ndt = (dt < 63) ? dt + 1 : 0;
                zt[buf ^ 1][sdl][snl] = zb[(ndt * 4 + sdl) * 1024 + snl];
                #pragma unroll
                for (int s = 0; s < 2; ++s) {
                    int idx = s * 256 + tid;
                    int dle = idx >> 7, jl = idx & 127;
                    el[buf ^ 1][dle][jl] =
                        embT[(ndt * 4 + dle) * 1024 + njc * NJ + jl];
                }
            }
            // compute 4 d's
            #pragma unroll
            for (int dl = 0; dl < 4; ++dl) {
                float4 za = *reinterpret_cast<float4*>(&zt[buf][dl][ty * 8]);
                float4 zc = *reinterpret_cast<float4*>(&zt[buf][dl][ty * 8 + 4]);
                float4 ev = *reinterpret_cast<float4*>(&el[buf][dl][tx * 4]);
                float zr[MR] = {za.x, za.y, za.z, za.w, zc.x, zc.y, zc.z, zc.w};
                float er[NR] = {ev.x, ev.y, ev.z, ev.w};
                #pragma unroll
                for (int m = 0; m < MR; ++m)
                    #pragma unroll
                    for (int q = 0; q < NR; ++q)
                        acc[m][q] += zr[m] * er[q];
            }
            __syncthreads();
        }

        // fold this j-chunk into running argmin (j ascending -> strict <)
        #pragma unroll
        for (int q = 0; q < NR; ++q) {
            int j = jc * NJ + tx * NR + q;
            float en = ws[WS_ENORM + j];
            #pragma unroll
            for (int m = 0; m < MR; ++m) {
                float v = en - 2.f * acc[m][q];   // dist minus const ||z||^2
                if (v < best[m]) { best[m] = v; bj[m] = j; }
            }
        }
    }

    // reduce argmin across the 32 tx-threads (lanes tx = lane&31)
    #pragma unroll
    for (int m = 0; m < MR; ++m) {
        float v = best[m]; int j = bj[m];
        #pragma unroll
        for (int o = 1; o < 32; o <<= 1) {
            float ov = __shfl_xor(v, o, 64);
            int   oj = __shfl_xor(j, o, 64);
            if (ov < v || (ov == v && oj < j)) { v = ov; j = oj; }
        }
        if (tx == 0) {
            int nl = ty * MR + m;
            out[OFF_IDX + n0 + nl] = (float)j;
            js_s[nl] = j;
            atomicAdd(out + OFF_CS + j, 1.0f);
            lsum += v;
        }
    }
    if (tx == 0) atomicAdd(out + OFF_LOSS, lsum);
    __syncthreads();

    // epilogue: z_q gather (coalesced along n) + dw atomics
    const long zqb = (long)OFF_ZQ + (long)b * (D_DIM * 1024) + hw0;
    #pragma unroll 4
    for (int rep = 0; rep < 64; ++rep) {
        int elem = rep * 256 + tid;          // 0..16383
        int d    = elem >> 6;
        int nl   = elem & 63;
        int j    = js_s[nl];
        out[zqb + d * 1024 + nl] = emb[j * D_DIM + d];
        atomicAdd(out + OFF_EMAW + j * D_DIM + d, zb[d * 1024 + nl]);
    }
}

// ---------------------------------------------------------------- cluster size + loss
__global__ void k_cs(const float* __restrict__ ema_cs, const float* __restrict__ ws,
                     float* __restrict__ out) {
    __shared__ float red[K_CODES];
    int j = threadIdx.x;                     // 1024 threads
    float raw = ema_cs[j] * DECAY + (1.f - DECAY) * out[OFF_CS + j];
    red[j] = raw;
    __syncthreads();
    for (int s = 512; s > 0; s >>= 1) {
        if (j < s) red[j] += red[j + s];
        __syncthreads();
    }
    float ntot = red[0];
    float cs = (raw + EPSV) / (ntot + K_CODES * EPSV) * ntot;
    out[OFF_CS + j] = cs;
    if (j == 0)
        out[OFF_LOSS] = BETA * (out[OFF_LOSS] + ws[WS_SZN]) / (float)(N_VEC * D_DIM);
}

// ---------------------------------------------------------------- embedding update
__global__ void k_emb(const float* __restrict__ ema_w, float* __restrict__ out) {
    int i = blockIdx.x * 256 + threadIdx.x;  // 1024 blocks -> 262144
    int j = i >> 8;
    float dw = out[OFF_EMAW + i];
    float nw = ema_w[i] * DECAY + (1.f - DECAY) * dw;
    out[OFF_EMAW + i] = nw;
    out[OFF_EMB + i]  = nw / out[OFF_CS + j];
}

// ---------------------------------------------------------------- launch
extern "C" void kernel_launch(void* const* d_in, const int* in_sizes, int n_in,
                              void* d_out, int out_size, void* d_ws, size_t ws_size,
                              hipStream_t stream) {
    const float* z      = (const float*)d_in[0];
    const float* emb    = (const float*)d_in[1];
    const float* ema_cs = (const float*)d_in[2];
    const float* ema_w  = (const float*)d_in[3];
    float* out = (float*)d_out;
    float* ws  = (float*)d_ws;               // needs ~1.03 MB

    hipLaunchKernelGGL(k_init, dim3(1024), dim3(256), 0, stream, out, ws);
    hipLaunchKernelGGL(k_prep, dim3(256),  dim3(256), 0, stream, emb, ws);
    hipLaunchKernelGGL(k_zn,   dim3(8192), dim3(256), 0, stream, z, ws);
    hipLaunchKernelGGL(k_main, dim3(N_VEC / BM), dim3(256), 0, stream, z, emb, ws, out);
    hipLaunchKernelGGL(k_cs,   dim3(1),    dim3(1024), 0, stream, ema_cs, ws, out);
    hipLaunchKernelGGL(k_emb,  dim3(1024), dim3(256), 0, stream, ema_w, out);
}

// Round 4
// 1234.377 us; speedup vs baseline: 2.7101x; 1.5131x over previous
//
#include <hip/hip_runtime.h>

#define K_CODES 1024
#define D_DIM   256
#define N_VEC   32768
#define BETA    0.25f
#define DECAY   0.99f
#define EPSV    1e-5f

// d_out layout (float32), offsets in elements
#define OFF_ZQ   0
#define OFF_IDX  8388608
#define OFF_LOSS 8421376
#define OFF_EMB  8421377
#define OFF_CS   8683521
#define OFF_EMAW 8684545

// ws layout (floats): embT[256][1024] | enorm[1024] | sum_znorm
#define WS_ENORM 262144
#define WS_SZN   263168

#define BM 32     // n per block
#define NJ 256    // j per outer chunk
#define MR 4      // n per thread
#define NR 8      // j per thread

// ---------------------------------------------------------------- init
__global__ void k_init(float* __restrict__ out, float* __restrict__ ws) {
    int i = blockIdx.x * 256 + threadIdx.x;   // 1024*256 = 262144
    if (i == 0) { out[OFF_LOSS] = 0.f; ws[WS_SZN] = 0.f; }
    if (i < K_CODES) out[OFF_CS + i] = 0.f;
    out[OFF_EMAW + i] = 0.f;
}

// ---------------------------------------------------------------- embT + ||e||^2
__global__ void k_prep(const float* __restrict__ emb, float* __restrict__ ws) {
    int j    = blockIdx.x * 4 + (threadIdx.x >> 6);   // 256 blocks, wave per row
    int lane = threadIdx.x & 63;
    float4 v = reinterpret_cast<const float4*>(emb + j * D_DIM)[lane];
    ws[(lane * 4 + 0) * 1024 + j] = v.x;
    ws[(lane * 4 + 1) * 1024 + j] = v.y;
    ws[(lane * 4 + 2) * 1024 + j] = v.z;
    ws[(lane * 4 + 3) * 1024 + j] = v.w;
    float s = v.x * v.x + v.y * v.y + v.z * v.z + v.w * v.w;
    #pragma unroll
    for (int o = 32; o > 0; o >>= 1) s += __shfl_xor(s, o, 64);
    if (lane == 0) ws[WS_ENORM + j] = s;
}

// ---------------------------------------------------------------- sum ||z||^2
__global__ void k_zn(const float* __restrict__ z, float* __restrict__ ws) {
    int i = blockIdx.x * 256 + threadIdx.x;   // 8192 blocks -> 2.1M float4
    float4 v = reinterpret_cast<const float4*>(z)[i];
    float s = v.x * v.x + v.y * v.y + v.z * v.z + v.w * v.w;
    #pragma unroll
    for (int o = 32; o > 0; o >>= 1) s += __shfl_xor(s, o, 64);
    if ((threadIdx.x & 63) == 0) atomicAdd(ws + WS_SZN, s);
}

// ---------------------------------------------------------------- main
__global__ __launch_bounds__(256, 2)
void k_main(const float* __restrict__ z, const float* __restrict__ emb,
            const float* __restrict__ ws, float* __restrict__ out) {
    __shared__ float zt[BM][260];   // 33.3 KB; stride 260 -> b128 reads tile 32 banks
    __shared__ int   js_s[BM];

    const int tid = threadIdx.x;    // 256 threads
    const int tx  = tid & 31;       // j-group: owns j = jc*256 + tx*8 .. +7
    const int g   = tid >> 5;       // n-group: owns n = g*4 .. g*4+3
    const int n0  = blockIdx.x * BM;  // 1024 blocks
    const int b   = n0 >> 10;
    const int hw0 = n0 & 1023;
    const float* zb   = z + b * (D_DIM * 1024) + hw0;
    const float* embT = ws;

    // ---- stage z tile ONCE (coalesced 128B rows)
    #pragma unroll
    for (int rep = 0; rep < 32; ++rep) {
        int flat = rep * 256 + tid;      // 0..8191
        int d    = flat >> 5;
        int nl   = flat & 31;
        zt[nl][d] = zb[d * 1024 + nl];
    }
    __syncthreads();

    float best[MR]; int bj[MR];
    #pragma unroll
    for (int m = 0; m < MR; ++m) { best[m] = 3.4e38f; bj[m] = 0; }
    float lsum = 0.f;

    // ---- main loop: NO barriers, e operands straight from L1/L2
    for (int jc = 0; jc < 4; ++jc) {
        const int jbase = jc * NJ + tx * NR;
        float acc[MR][NR];
        #pragma unroll
        for (int m = 0; m < MR; ++m)
            #pragma unroll
            for (int q = 0; q < NR; ++q) acc[m][q] = 0.f;

        for (int dt = 0; dt < 64; ++dt) {        // 4 d per iter
            float4 zr4[MR];
            #pragma unroll
            for (int m = 0; m < MR; ++m)
                zr4[m] = *reinterpret_cast<const float4*>(&zt[g * 4 + m][dt * 4]);
            #pragma unroll
            for (int dl = 0; dl < 4; ++dl) {
                const float* ed = embT + (dt * 4 + dl) * 1024 + jbase;
                float4 e0 = *reinterpret_cast<const float4*>(ed);
                float4 e1 = *reinterpret_cast<const float4*>(ed + 4);
                float er[NR] = {e0.x, e0.y, e0.z, e0.w, e1.x, e1.y, e1.z, e1.w};
                float zr[MR] = {reinterpret_cast<const float*>(&zr4[0])[dl],
                                reinterpret_cast<const float*>(&zr4[1])[dl],
                                reinterpret_cast<const float*>(&zr4[2])[dl],
                                reinterpret_cast<const float*>(&zr4[3])[dl]};
                #pragma unroll
                for (int m = 0; m < MR; ++m)
                    #pragma unroll
                    for (int q = 0; q < NR; ++q)
                        acc[m][q] += zr[m] * er[q];
            }
        }

        // fold into running argmin (j ascending, strict < -> np.argmin tie rule)
        float4 en0 = *reinterpret_cast<const float4*>(ws + WS_ENORM + jbase);
        float4 en1 = *reinterpret_cast<const float4*>(ws + WS_ENORM + jbase + 4);
        float en[NR] = {en0.x, en0.y, en0.z, en0.w, en1.x, en1.y, en1.z, en1.w};
        #pragma unroll
        for (int q = 0; q < NR; ++q) {
            int j = jbase + q;
            #pragma unroll
            for (int m = 0; m < MR; ++m) {
                float v = en[q] - 2.f * acc[m][q];   // dist minus const ||z||^2
                if (v < best[m]) { best[m] = v; bj[m] = j; }
            }
        }
    }

    // ---- reduce argmin across the 32 tx-lanes of each half-wave
    #pragma unroll
    for (int m = 0; m < MR; ++m) {
        float v = best[m]; int j = bj[m];
        #pragma unroll
        for (int o = 1; o < 32; o <<= 1) {
            float ov = __shfl_xor(v, o, 64);
            int   oj = __shfl_xor(j, o, 64);
            if (ov < v || (ov == v && oj < j)) { v = ov; j = oj; }
        }
        if (tx == 0) {
            int nl = g * 4 + m;
            out[OFF_IDX + n0 + nl] = (float)j;
            js_s[nl] = j;
            atomicAdd(out + OFF_CS + j, 1.0f);
            lsum += v;
        }
    }
    if (tx == 0) atomicAdd(out + OFF_LOSS, lsum);
    __syncthreads();

    // ---- epilogue: z_q gather (coalesced along n) + dw atomics
    const long zqb = (long)OFF_ZQ + (long)b * (D_DIM * 1024) + hw0;
    #pragma unroll 4
    for (int rep = 0; rep < 32; ++rep) {
        int elem = rep * 256 + tid;          // 0..8191
        int d    = elem >> 5;
        int nl   = elem & 31;
        int j    = js_s[nl];
        out[zqb + d * 1024 + nl] = emb[j * D_DIM + d];
        atomicAdd(out + OFF_EMAW + j * D_DIM + d, zt[nl][d]);
    }
}

// ---------------------------------------------------------------- cluster size + loss
__global__ void k_cs(const float* __restrict__ ema_cs, const float* __restrict__ ws,
                     float* __restrict__ out) {
    __shared__ float red[K_CODES];
    int j = threadIdx.x;                     // 1024 threads
    float raw = ema_cs[j] * DECAY + (1.f - DECAY) * out[OFF_CS + j];
    red[j] = raw;
    __syncthreads();
    for (int s = 512; s > 0; s >>= 1) {
        if (j < s) red[j] += red[j + s];
        __syncthreads();
    }
    float ntot = red[0];
    float cs = (raw + EPSV) / (ntot + K_CODES * EPSV) * ntot;
    out[OFF_CS + j] = cs;
    if (j == 0)
        out[OFF_LOSS] = BETA * (out[OFF_LOSS] + ws[WS_SZN]) / (float)(N_VEC * D_DIM);
}

// ---------------------------------------------------------------- embedding update
__global__ void k_emb(const float* __restrict__ ema_w, float* __restrict__ out) {
    int i = blockIdx.x * 256 + threadIdx.x;  // 1024 blocks -> 262144
    int j = i >> 8;
    float dw = out[OFF_EMAW + i];
    float nw = ema_w[i] * DECAY + (1.f - DECAY) * dw;
    out[OFF_EMAW + i] = nw;
    out[OFF_EMB + i]  = nw / out[OFF_CS + j];
}

// ---------------------------------------------------------------- launch
extern "C" void kernel_launch(void* const* d_in, const int* in_sizes, int n_in,
                              void* d_out, int out_size, void* d_ws, size_t ws_size,
                              hipStream_t stream) {
    const float* z      = (const float*)d_in[0];
    const float* emb    = (const float*)d_in[1];
    const float* ema_cs = (const float*)d_in[2];
    const float* ema_w  = (const float*)d_in[3];
    float* out = (float*)d_out;
    float* ws  = (float*)d_ws;               // needs ~1.03 MB

    hipLaunchKernelGGL(k_init, dim3(1024), dim3(256), 0, stream, out, ws);
    hipLaunchKernelGGL(k_prep, dim3(256),  dim3(256), 0, stream, emb, ws);
    hipLaunchKernelGGL(k_zn,   dim3(8192), dim3(256), 0, stream, z, ws);
    hipLaunchKernelGGL(k_main, dim3(N_VEC / BM), dim3(256), 0, stream, z, emb, ws, out);
    hipLaunchKernelGGL(k_cs,   dim3(1),    dim3(1024), 0, stream, ema_cs, ws, out);
    hipLaunchKernelGGL(k_emb,  dim3(1024), dim3(256), 0, stream, ema_w, out);
}

// Round 5
// 1080.066 us; speedup vs baseline: 3.0973x; 1.1429x over previous
//
#include <hip/hip_runtime.h>

#define K_CODES 1024
#define D_DIM   256
#define N_VEC   32768
#define BETA    0.25f
#define DECAY   0.99f
#define EPSV    1e-5f

// d_out layout (float32), offsets in elements
#define OFF_ZQ   0
#define OFF_IDX  8388608
#define OFF_LOSS 8421376
#define OFF_EMB  8421377
#define OFF_CS   8683521
#define OFF_EMAW 8684545     // doubles as B_swz (fp16) until k_zero2

// scratch parked in the z_q region (overwritten by k_epi, which runs after k_fix)
#define SC_FIXCNT  0
#define SC_FIXLIST 64        // capacity 32768

// ws layout (floats)
#define WS_EMBT   0          // embT[d][j] fp32 (for k_fix)
#define WS_ENORM  262144
#define WS_ELOMAX 263168

typedef _Float16 f16;
typedef f16   f16x8 __attribute__((ext_vector_type(8)));
typedef float f32x4 __attribute__((ext_vector_type(4)));

__device__ inline void top2_fold(float v, int j, float& d1, int& j1, float& d2, int& j2) {
    if (v < d1 || (v == d1 && j < j1)) { d2 = d1; j2 = j1; d1 = v; j1 = j; }
    else if (v < d2 || (v == d2 && j < j2)) { d2 = v; j2 = j; }
}
__device__ inline void top2_merge(float& d1, int& j1, float& d2, int& j2,
                                  float od1, int oj1, float od2, int oj2) {
    if (od1 < d1 || (od1 == d1 && oj1 < j1)) {
        // other's best wins; second = better(my best, other's second)
        float nd2; int nj2;
        if (d1 < od2 || (d1 == od2 && j1 < oj2)) { nd2 = d1; nj2 = j1; }
        else { nd2 = od2; nj2 = oj2; }
        d2 = nd2; j2 = nj2; d1 = od1; j1 = oj1;
    } else {
        if (od1 < d2 || (od1 == d2 && oj1 < j2)) { d2 = od1; j2 = oj1; }
    }
}

// ---------------------------------------------------------------- init
__global__ void k_init(float* __restrict__ out, float* __restrict__ ws) {
    int i = blockIdx.x * 256 + threadIdx.x;      // 8 blocks
    if (i == 0) { out[OFF_LOSS] = 0.f; out[SC_FIXCNT] = 0.f; ws[WS_ELOMAX] = 0.f; }
    if (i < K_CODES) out[OFF_CS + i] = 0.f;
}

// ------------------------------------------------- embT + enorm + elomax
__global__ void k_prep(const float* __restrict__ emb, float* __restrict__ ws) {
    int j    = blockIdx.x * 4 + (threadIdx.x >> 6);   // 256 blocks, wave per row
    int lane = threadIdx.x & 63;
    float4 v = reinterpret_cast<const float4*>(emb + j * D_DIM)[lane];
    ws[(lane * 4 + 0) * 1024 + j] = v.x;
    ws[(lane * 4 + 1) * 1024 + j] = v.y;
    ws[(lane * 4 + 2) * 1024 + j] = v.z;
    ws[(lane * 4 + 3) * 1024 + j] = v.w;
    float s = v.x * v.x + v.y * v.y + v.z * v.z + v.w * v.w;
    float lx = v.x - (float)(f16)v.x, ly = v.y - (float)(f16)v.y;
    float lz = v.z - (float)(f16)v.z, lw = v.w - (float)(f16)v.w;
    float sl = lx * lx + ly * ly + lz * lz + lw * lw;
    #pragma unroll
    for (int o = 32; o > 0; o >>= 1) { s += __shfl_xor(s, o, 64); sl += __shfl_xor(sl, o, 64); }
    if (lane == 0) {
        ws[WS_ENORM + j] = s;
        atomicMax((int*)(ws + WS_ELOMAX), __float_as_int(sqrtf(sl)));
    }
}

// ------------------------------------------------- B_swz (fp16 fragment order)
// slot = ((jt*8 + kb)*64 + lane); lane holds B[k=kb*32+(lane>>4)*8 ..+7][j=jt*16+(lane&15)]
__global__ void k_prep_b(const float* __restrict__ emb, float* __restrict__ out) {
    int slot = blockIdx.x * 256 + threadIdx.x;   // 128 blocks -> 32768 slots
    int lane = slot & 63;
    int kbjt = slot >> 6;
    int kb   = kbjt & 7;
    int jt   = kbjt >> 3;
    int j    = jt * 16 + (lane & 15);
    int d0   = kb * 32 + (lane >> 4) * 8;
    float4 e0 = *reinterpret_cast<const float4*>(emb + j * D_DIM + d0);
    float4 e1 = *reinterpret_cast<const float4*>(emb + j * D_DIM + d0 + 4);
    f16x8 w;
    w[0] = (f16)e0.x; w[1] = (f16)e0.y; w[2] = (f16)e0.z; w[3] = (f16)e0.w;
    w[4] = (f16)e1.x; w[5] = (f16)e1.y; w[6] = (f16)e1.z; w[7] = (f16)e1.w;
    f16* dst = (f16*)(out + OFF_EMAW);
    *reinterpret_cast<f16x8*>(dst + slot * 8) = w;
}

// ---------------------------------------------------------------- main (MFMA)
__global__ __launch_bounds__(512, 2)
void k_main(const float* __restrict__ z, const float* __restrict__ ws,
            float* __restrict__ out) {
    __shared__ f16   zl[64][520];     // [n][k]: k<256 hi, 256.. lo; pad 8 -> 66.6 KB
    __shared__ float els[K_CODES];
    __shared__ float red[64][8][4];   // per row per wave: d1,j1,d2,j2
    __shared__ float znl[64];

    const int tid  = threadIdx.x;     // 512
    const int lane = tid & 63;
    const int w    = tid >> 6;        // wave 0..7 -> j-slice of 128
    const int n0   = blockIdx.x * 64; // 512 blocks
    const int b    = n0 >> 10;
    const int hw0  = n0 & 1023;
    const float* zb = z + b * (D_DIM * 1024) + hw0;

    // ---- stage z tile as fp16 hi/lo (coalesced float4 along n)
    #pragma unroll
    for (int rep = 0; rep < 8; ++rep) {
        int flat = rep * 512 + tid;          // 0..4095
        int d    = flat >> 4;
        int n4   = (flat & 15) * 4;
        float4 v = *reinterpret_cast<const float4*>(zb + d * 1024 + n4);
        float vv[4] = {v.x, v.y, v.z, v.w};
        #pragma unroll
        for (int c = 0; c < 4; ++c) {
            f16 hi = (f16)vv[c];
            f16 lo = (f16)(vv[c] - (float)hi);
            zl[n4 + c][d]       = hi;
            zl[n4 + c][256 + d] = lo;
        }
    }
    #pragma unroll
    for (int rep = 0; rep < 2; ++rep) {
        int j = rep * 512 + tid;
        els[j] = ws[WS_ENORM + j];
    }
    __syncthreads();

    // ---- znorm per row (from hi+lo; slop covered by margin)
    if (tid < 64) {
        float s = 0.f;
        for (int d = 0; d < 256; ++d) {
            float q = (float)zl[tid][d] + (float)zl[tid][256 + d];
            s += q * q;
        }
        znl[tid] = s;
    }

    // ---- MFMA k-loop: K=512 (hi 0..255 vs e_hi, lo 256..511 vs e_hi)
    const f16* Bw = (const f16*)(out + OFF_EMAW);
    const int arow = lane & 15, aoff = (lane >> 4) * 8;
    const int jt0 = w * 8;
    f32x4 acc[4][8];
    #pragma unroll
    for (int i = 0; i < 4; ++i)
        #pragma unroll
        for (int q = 0; q < 8; ++q) acc[i][q] = (f32x4){0.f, 0.f, 0.f, 0.f};

    for (int kt = 0; kt < 16; ++kt) {
        int kb   = kt & 7;
        int koff = ((kt & 8) ? 256 : 0) + kb * 32 + aoff;
        f16x8 a[4];
        #pragma unroll
        for (int i = 0; i < 4; ++i)
            a[i] = *reinterpret_cast<const f16x8*>(&zl[i * 16 + arow][koff]);
        #pragma unroll
        for (int q = 0; q < 8; ++q) {
            f16x8 bq = *reinterpret_cast<const f16x8*>(
                Bw + (((jt0 + q) * 8 + kb) * 64 + lane) * 8);
            #pragma unroll
            for (int i = 0; i < 4; ++i)
                acc[i][q] = __builtin_amdgcn_mfma_f32_16x16x32_f16(a[i], bq, acc[i][q], 0, 0, 0);
        }
    }
    __syncthreads();

    // ---- top-2 per row over this wave's 128 j, then cross-wave
    #pragma unroll
    for (int i = 0; i < 4; ++i) {
        #pragma unroll
        for (int r = 0; r < 4; ++r) {
            float d1 = 3.4e38f, d2 = 3.4e38f; int j1 = -1, j2 = -1;
            #pragma unroll
            for (int q = 0; q < 8; ++q) {
                int j = (jt0 + q) * 16 + (lane & 15);
                float v = els[j] - 2.f * acc[i][q][r];
                top2_fold(v, j, d1, j1, d2, j2);
            }
            #pragma unroll
            for (int s = 1; s < 16; s <<= 1) {
                float od1 = __shfl_xor(d1, s, 64); int oj1 = __shfl_xor(j1, s, 64);
                float od2 = __shfl_xor(d2, s, 64); int oj2 = __shfl_xor(j2, s, 64);
                top2_merge(d1, j1, d2, j2, od1, oj1, od2, oj2);
            }
            if ((lane & 15) == 0) {
                int row = i * 16 + (lane >> 4) * 4 + r;
                red[row][w][0] = d1; red[row][w][1] = (float)j1;
                red[row][w][2] = d2; red[row][w][3] = (float)j2;
            }
        }
    }
    __syncthreads();

    if (tid < 64) {
        int row = tid;
        float d1 = red[row][0][0], d2 = red[row][0][2];
        int   j1 = (int)red[row][0][1], j2 = (int)red[row][0][3];
        #pragma unroll
        for (int ww = 1; ww < 8; ++ww)
            top2_merge(d1, j1, d2, j2, red[row][ww][0], (int)red[row][ww][1],
                       red[row][ww][2], (int)red[row][ww][3]);
        int n = n0 + row;
        out[OFF_IDX + n] = (float)j1;
        float margin = 4.f * sqrtf(znl[row]) * ws[WS_ELOMAX] + 0.01f;
        if (d2 - d1 <= margin) {
            int p = atomicAdd((int*)(out + SC_FIXCNT), 1);
            out[SC_FIXLIST + p] = (float)n;
        }
    }
}

// ---------------------------------------------------------------- zero dw region
__global__ void k_zero2(float* __restrict__ out) {
    int i = blockIdx.x * 256 + threadIdx.x;      // 1024 blocks
    out[OFF_EMAW + i] = 0.f;
}

// ---------------------------------------------------------------- exact recompute of flagged rows
__global__ void k_fix(const float* __restrict__ z, const float* __restrict__ ws,
                      float* __restrict__ out) {
    __shared__ float zv[D_DIM];
    __shared__ float rd[4]; __shared__ int rj[4];
    const int tid = threadIdx.x;                 // 256
    const int cnt = *(const int*)(out + SC_FIXCNT);
    for (int fi = blockIdx.x; fi < cnt; fi += gridDim.x) {
        int n  = (int)out[SC_FIXLIST + fi];
        int b  = n >> 10, hw = n & 1023;
        zv[tid] = z[b * (D_DIM * 1024) + tid * 1024 + hw];
        __syncthreads();
        float best = 3.4e38f; int bj = 0;
        float dot[4] = {0.f, 0.f, 0.f, 0.f};
        for (int d = 0; d < 256; ++d) {
            float zd = zv[d];
            float4 e = *reinterpret_cast<const float4*>(ws + WS_EMBT + d * 1024 + tid * 4);
            dot[0] += zd * e.x; dot[1] += zd * e.y; dot[2] += zd * e.z; dot[3] += zd * e.w;
        }
        #pragma unroll
        for (int q = 0; q < 4; ++q) {
            int j = tid * 4 + q;
            float v = ws[WS_ENORM + j] - 2.f * dot[q];
            if (v < best || (v == best && j < bj)) { best = v; bj = j; }
        }
        #pragma unroll
        for (int o = 1; o < 64; o <<= 1) {
            float ov = __shfl_xor(best, o, 64);
            int   oj = __shfl_xor(bj, o, 64);
            if (ov < best || (ov == best && oj < bj)) { best = ov; bj = oj; }
        }
        if ((tid & 63) == 0) { rd[tid >> 6] = best; rj[tid >> 6] = bj; }
        __syncthreads();
        if (tid == 0) {
            float v = rd[0]; int j = rj[0];
            #pragma unroll
            for (int ww = 1; ww < 4; ++ww)
                if (rd[ww] < v || (rd[ww] == v && rj[ww] < j)) { v = rd[ww]; j = rj[ww]; }
            out[OFF_IDX + n] = (float)j;
        }
        __syncthreads();
    }
}

// ---------------------------------------------------------------- epilogue: zq + counts + dw + loss
__global__ void k_epi(const float* __restrict__ z, const float* __restrict__ emb,
                      float* __restrict__ out) {
    __shared__ int js[32];
    const int tid = threadIdx.x;                 // 256
    const int n0  = blockIdx.x * 32;             // 1024 blocks
    const int b   = n0 >> 10;
    const int hw0 = n0 & 1023;
    if (tid < 32) js[tid] = (int)out[OFF_IDX + n0 + tid];
    __syncthreads();
    const long zqb = (long)b * (D_DIM * 1024) + hw0;
    float ls = 0.f;
    #pragma unroll 4
    for (int rep = 0; rep < 32; ++rep) {
        int elem = rep * 256 + tid;              // 0..8191
        int d    = elem >> 5;
        int nl   = elem & 31;
        int j    = js[nl];
        float zq = emb[j * D_DIM + d];
        float zv = z[zqb + d * 1024 + nl];
        out[OFF_ZQ + zqb + d * 1024 + nl] = zq;
        atomicAdd(out + OFF_EMAW + j * D_DIM + d, zv);
        float df = zq - zv; ls += df * df;
    }
    if (tid < 32) atomicAdd(out + OFF_CS + js[tid], 1.0f);
    #pragma unroll
    for (int o = 32; o > 0; o >>= 1) ls += __shfl_xor(ls, o, 64);
    if ((tid & 63) == 0) atomicAdd(out + OFF_LOSS, ls);
}

// ---------------------------------------------------------------- cluster size + loss
__global__ void k_cs(const float* __restrict__ ema_cs, float* __restrict__ out) {
    __shared__ float red[K_CODES];
    int j = threadIdx.x;                         // 1024 threads
    float raw = ema_cs[j] * DECAY + (1.f - DECAY) * out[OFF_CS + j];
    red[j] = raw;
    __syncthreads();
    for (int s = 512; s > 0; s >>= 1) {
        if (j < s) red[j] += red[j + s];
        __syncthreads();
    }
    float ntot = red[0];
    float cs = (raw + EPSV) / (ntot + K_CODES * EPSV) * ntot;
    out[OFF_CS + j] = cs;
    if (j == 0) out[OFF_LOSS] = BETA * out[OFF_LOSS] / (float)(N_VEC * D_DIM);
}

// ---------------------------------------------------------------- embedding update
__global__ void k_emb(const float* __restrict__ ema_w, float* __restrict__ out) {
    int i = blockIdx.x * 256 + threadIdx.x;      // 1024 blocks
    int j = i >> 8;
    float dw = out[OFF_EMAW + i];
    float nw = ema_w[i] * DECAY + (1.f - DECAY) * dw;
    out[OFF_EMAW + i] = nw;
    out[OFF_EMB + i]  = nw / out[OFF_CS + j];
}

// ---------------------------------------------------------------- launch
extern "C" void kernel_launch(void* const* d_in, const int* in_sizes, int n_in,
                              void* d_out, int out_size, void* d_ws, size_t ws_size,
                              hipStream_t stream) {
    const float* z      = (const float*)d_in[0];
    const float* emb    = (const float*)d_in[1];
    const float* ema_cs = (const float*)d_in[2];
    const float* ema_w  = (const float*)d_in[3];
    float* out = (float*)d_out;
    float* ws  = (float*)d_ws;                   // ~1.05 MB used

    hipLaunchKernelGGL(k_init,   dim3(8),    dim3(256),  0, stream, out, ws);
    hipLaunchKernelGGL(k_prep,   dim3(256),  dim3(256),  0, stream, emb, ws);
    hipLaunchKernelGGL(k_prep_b, dim3(128),  dim3(256),  0, stream, emb, out);
    hipLaunchKernelGGL(k_main,   dim3(512),  dim3(512),  0, stream, z, ws, out);
    hipLaunchKernelGGL(k_zero2,  dim3(1024), dim3(256),  0, stream, out);
    hipLaunchKernelGGL(k_fix,    dim3(128),  dim3(256),  0, stream, z, ws, out);
    hipLaunchKernelGGL(k_epi,    dim3(1024), dim3(256),  0, stream, z, emb, out);
    hipLaunchKernelGGL(k_cs,     dim3(1),    dim3(1024), 0, stream, ema_cs, out);
    hipLaunchKernelGGL(k_emb,    dim3(1024), dim3(256),  0, stream, ema_w, out);
}

// Round 6
// 750.211 us; speedup vs baseline: 4.4591x; 1.4397x over previous
//
#include <hip/hip_runtime.h>

#define K_CODES 1024
#define D_DIM   256
#define N_VEC   32768
#define BETA    0.25f
#define DECAY   0.99f
#define EPSV    1e-5f

// d_out layout (float32), offsets in elements
#define OFF_ZQ   0          // also parks zf[n][d] (k_trans -> k_fix/k_dw), overwritten by k_epi
#define OFF_IDX  8388608
#define OFF_LOSS 8421376
#define OFF_EMB  8421377
#define OFF_CS   8683521    // counts -> new_cs (k_scan, in place)
#define OFF_EMAW 8684545    // B_swz fp16 until k_dw overwrites with new_ema_w

// ws layout (floats / ints)
#define WS_EMBT    0        // embT[d][j] fp32 (262144)
#define WS_ENORM   262144   // 1024
#define WS_ELOMAX  263168
#define WS_FIXCNT  263169
#define WS_FIXLIST 263424   // 32768 ints; reused as BUCKET by k_scatter/k_dw
#define WS_OFF     296192   // 1024 ints
#define WS_POS     297216   // 1024 ints
#define WS_CNT     298240   // 1024 ints   (total ~1.2 MB)

typedef _Float16 f16;
typedef f16   f16x8 __attribute__((ext_vector_type(8)));
typedef float f32x4 __attribute__((ext_vector_type(4)));

__device__ inline void top2_fold(float v, int j, float& d1, int& j1, float& d2, int& j2) {
    if (v < d1 || (v == d1 && j < j1)) { d2 = d1; j2 = j1; d1 = v; j1 = j; }
    else if (v < d2 || (v == d2 && j < j2)) { d2 = v; j2 = j; }
}
__device__ inline void top2_merge(float& d1, int& j1, float& d2, int& j2,
                                  float od1, int oj1, float od2, int oj2) {
    if (od1 < d1 || (od1 == d1 && oj1 < j1)) {
        float nd2; int nj2;
        if (d1 < od2 || (d1 == od2 && j1 < oj2)) { nd2 = d1; nj2 = j1; }
        else { nd2 = od2; nj2 = oj2; }
        d2 = nd2; j2 = nj2; d1 = od1; j1 = oj1;
    } else {
        if (od1 < d2 || (od1 == d2 && oj1 < j2)) { d2 = od1; j2 = oj1; }
    }
}

// ---------------------------------------------------------------- init
__global__ void k_init(float* __restrict__ out, float* __restrict__ ws) {
    int i = threadIdx.x;                         // 1 block x 1024
    out[OFF_CS + i] = 0.f;
    if (i == 0) {
        out[OFF_LOSS] = 0.f;
        ws[WS_ELOMAX] = 0.f;
        *(int*)(ws + WS_FIXCNT) = 0;
    }
}

// ------------------------------------------------- embT + enorm + elomax
__global__ void k_prep(const float* __restrict__ emb, float* __restrict__ ws) {
    int j    = blockIdx.x * 4 + (threadIdx.x >> 6);   // 256 blocks
    int lane = threadIdx.x & 63;
    float4 v = reinterpret_cast<const float4*>(emb + j * D_DIM)[lane];
    ws[(lane * 4 + 0) * 1024 + j] = v.x;
    ws[(lane * 4 + 1) * 1024 + j] = v.y;
    ws[(lane * 4 + 2) * 1024 + j] = v.z;
    ws[(lane * 4 + 3) * 1024 + j] = v.w;
    float s = v.x * v.x + v.y * v.y + v.z * v.z + v.w * v.w;
    float lx = v.x - (float)(f16)v.x, ly = v.y - (float)(f16)v.y;
    float lz = v.z - (float)(f16)v.z, lw = v.w - (float)(f16)v.w;
    float sl = lx * lx + ly * ly + lz * lz + lw * lw;
    #pragma unroll
    for (int o = 32; o > 0; o >>= 1) { s += __shfl_xor(s, o, 64); sl += __shfl_xor(sl, o, 64); }
    if (lane == 0) {
        ws[WS_ENORM + j] = s;
        atomicMax((int*)(ws + WS_ELOMAX), __float_as_int(sqrtf(sl)));
    }
}

// ------------------------------------------------- B_swz (fp16 fragment order)
__global__ void k_prep_b(const float* __restrict__ emb, float* __restrict__ out) {
    int slot = blockIdx.x * 256 + threadIdx.x;   // 128 blocks -> 32768 slots
    int lane = slot & 63;
    int kbjt = slot >> 6;
    int kb   = kbjt & 7;
    int jt   = kbjt >> 3;
    int j    = jt * 16 + (lane & 15);
    int d0   = kb * 32 + (lane >> 4) * 8;
    float4 e0 = *reinterpret_cast<const float4*>(emb + j * D_DIM + d0);
    float4 e1 = *reinterpret_cast<const float4*>(emb + j * D_DIM + d0 + 4);
    f16x8 w;
    w[0] = (f16)e0.x; w[1] = (f16)e0.y; w[2] = (f16)e0.z; w[3] = (f16)e0.w;
    w[4] = (f16)e1.x; w[5] = (f16)e1.y; w[6] = (f16)e1.z; w[7] = (f16)e1.w;
    f16* dst = (f16*)(out + OFF_EMAW);
    *reinterpret_cast<f16x8*>(dst + slot * 8) = w;
}

// ------------------------------------------------- zf[n][d] row-major transpose
__global__ void k_trans(const float* __restrict__ z, float* __restrict__ out) {
    __shared__ float tile[32][33];
    int bid = blockIdx.x;                        // 8192 blocks
    int b   = bid >> 8;
    int rem = bid & 255;
    int d0  = (rem >> 5) * 32;
    int hw0 = (rem & 31) * 32;
    const int tid = threadIdx.x;                 // 256
    #pragma unroll
    for (int rep = 0; rep < 4; ++rep) {
        int elem = rep * 256 + tid;
        int dl = elem >> 5, hwl = elem & 31;
        tile[dl][hwl] = z[b * (D_DIM * 1024) + (d0 + dl) * 1024 + hw0 + hwl];
    }
    __syncthreads();
    #pragma unroll
    for (int rep = 0; rep < 4; ++rep) {
        int elem = rep * 256 + tid;
        int hwl = elem >> 5, dl = elem & 31;
        out[OFF_ZQ + (long)(b * 1024 + hw0 + hwl) * 256 + d0 + dl] = tile[dl][hwl];
    }
}

// ---------------------------------------------------------------- main (MFMA)
__global__ __launch_bounds__(512, 2)
void k_main(const float* __restrict__ z, float* __restrict__ ws,
            float* __restrict__ out) {
    __shared__ f16   zl[64][520];
    __shared__ float els[K_CODES];
    __shared__ float red[64][8][4];
    __shared__ float znl[64];

    const int tid  = threadIdx.x;     // 512
    const int lane = tid & 63;
    const int w    = tid >> 6;
    const int n0   = blockIdx.x * 64; // 512 blocks
    const int b    = n0 >> 10;
    const int hw0  = n0 & 1023;
    const float* zb = z + b * (D_DIM * 1024) + hw0;

    #pragma unroll
    for (int rep = 0; rep < 8; ++rep) {
        int flat = rep * 512 + tid;
        int d    = flat >> 4;
        int n4   = (flat & 15) * 4;
        float4 v = *reinterpret_cast<const float4*>(zb + d * 1024 + n4);
        float vv[4] = {v.x, v.y, v.z, v.w};
        #pragma unroll
        for (int c = 0; c < 4; ++c) {
            f16 hi = (f16)vv[c];
            f16 lo = (f16)(vv[c] - (float)hi);
            zl[n4 + c][d]       = hi;
            zl[n4 + c][256 + d] = lo;
        }
    }
    #pragma unroll
    for (int rep = 0; rep < 2; ++rep) {
        int j = rep * 512 + tid;
        els[j] = ws[WS_ENORM + j];
    }
    __syncthreads();

    if (tid < 64) {
        float s = 0.f;
        for (int d = 0; d < 256; ++d) {
            float q = (float)zl[tid][d] + (float)zl[tid][256 + d];
            s += q * q;
        }
        znl[tid] = s;
    }

    const f16* Bw = (const f16*)(out + OFF_EMAW);
    const int arow = lane & 15, aoff = (lane >> 4) * 8;
    const int jt0 = w * 8;
    f32x4 acc[4][8];
    #pragma unroll
    for (int i = 0; i < 4; ++i)
        #pragma unroll
        for (int q = 0; q < 8; ++q) acc[i][q] = (f32x4){0.f, 0.f, 0.f, 0.f};

    for (int kt = 0; kt < 16; ++kt) {
        int kb   = kt & 7;
        int koff = ((kt & 8) ? 256 : 0) + kb * 32 + aoff;
        f16x8 a[4];
        #pragma unroll
        for (int i = 0; i < 4; ++i)
            a[i] = *reinterpret_cast<const f16x8*>(&zl[i * 16 + arow][koff]);
        #pragma unroll
        for (int q = 0; q < 8; ++q) {
            f16x8 bq = *reinterpret_cast<const f16x8*>(
                Bw + (((jt0 + q) * 8 + kb) * 64 + lane) * 8);
            #pragma unroll
            for (int i = 0; i < 4; ++i)
                acc[i][q] = __builtin_amdgcn_mfma_f32_16x16x32_f16(a[i], bq, acc[i][q], 0, 0, 0);
        }
    }
    __syncthreads();

    #pragma unroll
    for (int i = 0; i < 4; ++i) {
        #pragma unroll
        for (int r = 0; r < 4; ++r) {
            float d1 = 3.4e38f, d2 = 3.4e38f; int j1 = -1, j2 = -1;
            #pragma unroll
            for (int q = 0; q < 8; ++q) {
                int j = (jt0 + q) * 16 + (lane & 15);
                float v = els[j] - 2.f * acc[i][q][r];
                top2_fold(v, j, d1, j1, d2, j2);
            }
            #pragma unroll
            for (int s = 1; s < 16; s <<= 1) {
                float od1 = __shfl_xor(d1, s, 64); int oj1 = __shfl_xor(j1, s, 64);
                float od2 = __shfl_xor(d2, s, 64); int oj2 = __shfl_xor(j2, s, 64);
                top2_merge(d1, j1, d2, j2, od1, oj1, od2, oj2);
            }
            if ((lane & 15) == 0) {
                int row = i * 16 + (lane >> 4) * 4 + r;
                red[row][w][0] = d1; red[row][w][1] = (float)j1;
                red[row][w][2] = d2; red[row][w][3] = (float)j2;
            }
        }
    }
    __syncthreads();

    if (tid < 64) {
        int row = tid;
        float d1 = red[row][0][0], d2 = red[row][0][2];
        int   j1 = (int)red[row][0][1], j2 = (int)red[row][0][3];
        #pragma unroll
        for (int ww = 1; ww < 8; ++ww)
            top2_merge(d1, j1, d2, j2, red[row][ww][0], (int)red[row][ww][1],
                       red[row][ww][2], (int)red[row][ww][3]);
        int n = n0 + row;
        out[OFF_IDX + n] = (float)j1;
        float margin = 4.f * sqrtf(znl[row]) * ws[WS_ELOMAX] + 0.05f;  // 2m bound
        if (d2 - d1 <= margin) {
            int p = atomicAdd((int*)(ws + WS_FIXCNT), 1);
            ((int*)(ws + WS_FIXLIST))[p] = n;
        }
    }
}

// ---------------------------------------------------------------- exact recompute (batched 8 rows)
__global__ void k_fix(const float* __restrict__ ws_c, float* __restrict__ ws,
                      float* __restrict__ out) {
    __shared__ float zr[8][256];
    __shared__ float rd[8][4]; __shared__ int rj[8][4];
    const int tid = threadIdx.x;                 // 256
    const int cnt = *(const int*)(ws_c + WS_FIXCNT);
    const int* fixlist = (const int*)(ws_c + WS_FIXLIST);
    const int groups = (cnt + 7) >> 3;
    const float4 en = *reinterpret_cast<const float4*>(ws_c + WS_ENORM + tid * 4);

    for (int g = blockIdx.x; g < groups; g += gridDim.x) {
        int nrow[8];
        #pragma unroll
        for (int r = 0; r < 8; ++r) {
            int slot = g * 8 + r;
            nrow[r] = (slot < cnt) ? fixlist[slot] : -1;
        }
        #pragma unroll
        for (int r = 0; r < 8; ++r)
            zr[r][tid] = (nrow[r] >= 0) ? out[OFF_ZQ + (long)nrow[r] * 256 + tid] : 0.f;
        __syncthreads();

        float acc[8][4];
        #pragma unroll
        for (int r = 0; r < 8; ++r)
            #pragma unroll
            for (int q = 0; q < 4; ++q) acc[r][q] = 0.f;
        for (int d = 0; d < 256; ++d) {
            float4 e = *reinterpret_cast<const float4*>(ws_c + WS_EMBT + d * 1024 + tid * 4);
            #pragma unroll
            for (int r = 0; r < 8; ++r) {
                float zd = zr[r][d];
                acc[r][0] += zd * e.x; acc[r][1] += zd * e.y;
                acc[r][2] += zd * e.z; acc[r][3] += zd * e.w;
            }
        }
        #pragma unroll
        for (int r = 0; r < 8; ++r) {
            float best = 3.4e38f; int bj = 0;
            #pragma unroll
            for (int q = 0; q < 4; ++q) {
                int j = tid * 4 + q;
                float v = ((const float*)&en)[q] - 2.f * acc[r][q];
                if (v < best || (v == best && j < bj)) { best = v; bj = j; }
            }
            #pragma unroll
            for (int o = 1; o < 64; o <<= 1) {
                float ov = __shfl_xor(best, o, 64);
                int   oj = __shfl_xor(bj, o, 64);
                if (ov < best || (ov == best && oj < bj)) { best = ov; bj = oj; }
            }
            if ((tid & 63) == 0) { rd[r][tid >> 6] = best; rj[r][tid >> 6] = bj; }
        }
        __syncthreads();
        if (tid < 8) {
            int r = tid;
            if (nrow[0] >= -1) {  // keep nrow live
                float v = rd[r][0]; int j = rj[r][0];
                #pragma unroll
                for (int ww = 1; ww < 4; ++ww)
                    if (rd[r][ww] < v || (rd[r][ww] == v && rj[r][ww] < j)) { v = rd[r][ww]; j = rj[r][ww]; }
                int slot = g * 8 + r;
                if (slot < cnt) out[OFF_IDX + fixlist[slot]] = (float)j;
            }
        }
        __syncthreads();
    }
}

// ---------------------------------------------------------------- counts
__global__ void k_count(float* __restrict__ out) {
    int n = blockIdx.x * 256 + threadIdx.x;      // 128 blocks
    int j = (int)out[OFF_IDX + n];
    atomicAdd(out + OFF_CS + j, 1.0f);
}

// ---------------------------------------------------------------- scan: offsets + new_cs
__global__ void k_scan(const float* __restrict__ ema_cs, float* __restrict__ ws,
                       float* __restrict__ out) {
    __shared__ float s[K_CODES];
    int tid = threadIdx.x;                       // 1024
    float cntf = out[OFF_CS + tid];
    float raw  = ema_cs[tid] * DECAY + 0.01f * cntf;
    s[tid] = cntf;
    __syncthreads();
    for (int off = 1; off < 1024; off <<= 1) {
        float v = (tid >= off) ? s[tid - off] : 0.f;
        __syncthreads();
        s[tid] += v;
        __syncthreads();
    }
    int excl = (int)(s[tid] - cntf);
    ((int*)(ws + WS_OFF))[tid] = excl;
    ((int*)(ws + WS_POS))[tid] = excl;
    ((int*)(ws + WS_CNT))[tid] = (int)cntf;
    __syncthreads();
    s[tid] = raw;
    __syncthreads();
    for (int st = 512; st > 0; st >>= 1) {
        if (tid < st) s[tid] += s[tid + st];
        __syncthreads();
    }
    float ntot = s[0];
    out[OFF_CS + tid] = (raw + EPSV) / (ntot + K_CODES * EPSV) * ntot;
}

// ---------------------------------------------------------------- scatter into buckets
__global__ void k_scatter(const float* __restrict__ out_c, float* __restrict__ ws) {
    int n = blockIdx.x * 256 + threadIdx.x;      // 128 blocks
    int j = (int)out_c[OFF_IDX + n];
    int p = atomicAdd((int*)(ws + WS_POS) + j, 1);
    ((int*)(ws + WS_FIXLIST))[p] = n;            // bucket reuses fixlist slot
}

// ---------------------------------------------------------------- dw + new_ema_w + new_embedding
__global__ void k_dw(const float* __restrict__ ema_w, const float* __restrict__ ws,
                     float* __restrict__ out) {
    const int j   = blockIdx.x;                  // 1024 blocks
    const int tid = threadIdx.x;                 // 256
    const int off = ((const int*)(ws + WS_OFF))[j];
    const int cnt = ((const int*)(ws + WS_CNT))[j];
    const int* bucket = (const int*)(ws + WS_FIXLIST);
    float acc = 0.f;
    for (int i = 0; i < cnt; ++i) {
        int n = bucket[off + i];
        acc += out[OFF_ZQ + (long)n * 256 + tid];
    }
    float nw = ema_w[j * 256 + tid] * DECAY + 0.01f * acc;
    out[OFF_EMAW + j * 256 + tid] = nw;
    out[OFF_EMB + j * 256 + tid]  = nw / out[OFF_CS + j];
}

// ---------------------------------------------------------------- z_q + loss (AFTER k_dw)
__global__ void k_epi(const float* __restrict__ z, const float* __restrict__ emb,
                      float* __restrict__ out) {
    __shared__ float erows[32][257];
    __shared__ int js[32];
    const int tid = threadIdx.x;                 // 256
    const int n0  = blockIdx.x * 32;             // 1024 blocks
    const int b   = n0 >> 10;
    const int hw0 = n0 & 1023;
    if (tid < 32) js[tid] = (int)out[OFF_IDX + n0 + tid];
    __syncthreads();
    #pragma unroll 4
    for (int r = 0; r < 32; ++r)
        erows[r][tid] = emb[js[r] * D_DIM + tid];
    __syncthreads();
    const long zqb = (long)b * (D_DIM * 1024) + hw0;
    float ls = 0.f;
    #pragma unroll 4
    for (int rep = 0; rep < 32; ++rep) {
        int elem = rep * 256 + tid;
        int d    = elem >> 5;
        int nl   = elem & 31;
        float zq = erows[nl][d];
        float zv = z[zqb + d * 1024 + nl];
        out[OFF_ZQ + zqb + d * 1024 + nl] = zq;
        float df = zq - zv; ls += df * df;
    }
    #pragma unroll
    for (int o = 32; o > 0; o >>= 1) ls += __shfl_xor(ls, o, 64);
    if ((tid & 63) == 0)
        atomicAdd(out + OFF_LOSS, ls * (BETA / (float)(N_VEC * D_DIM)));
}

// ---------------------------------------------------------------- launch
extern "C" void kernel_launch(void* const* d_in, const int* in_sizes, int n_in,
                              void* d_out, int out_size, void* d_ws, size_t ws_size,
                              hipStream_t stream) {
    const float* z      = (const float*)d_in[0];
    const float* emb    = (const float*)d_in[1];
    const float* ema_cs = (const float*)d_in[2];
    const float* ema_w  = (const float*)d_in[3];
    float* out = (float*)d_out;
    float* ws  = (float*)d_ws;                   // ~1.2 MB used

    hipLaunchKernelGGL(k_init,    dim3(1),    dim3(1024), 0, stream, out, ws);
    hipLaunchKernelGGL(k_prep,    dim3(256),  dim3(256),  0, stream, emb, ws);
    hipLaunchKernelGGL(k_prep_b,  dim3(128),  dim3(256),  0, stream, emb, out);
    hipLaunchKernelGGL(k_trans,   dim3(8192), dim3(256),  0, stream, z, out);
    hipLaunchKernelGGL(k_main,    dim3(512),  dim3(512),  0, stream, z, ws, out);
    hipLaunchKernelGGL(k_fix,     dim3(256),  dim3(256),  0, stream, ws, ws, out);
    hipLaunchKernelGGL(k_count,   dim3(128),  dim3(256),  0, stream, out);
    hipLaunchKernelGGL(k_scan,    dim3(1),    dim3(1024), 0, stream, ema_cs, ws, out);
    hipLaunchKernelGGL(k_scatter, dim3(128),  dim3(256),  0, stream, out, ws);
    hipLaunchKernelGGL(k_dw,      dim3(1024), dim3(256),  0, stream, ema_w, ws, out);
    hipLaunchKernelGGL(k_epi,     dim3(1024), dim3(256),  0, stream, z, emb, out);
}

// Round 7
// 433.314 us; speedup vs baseline: 7.7203x; 1.7313x over previous
//
#include <hip/hip_runtime.h>

#define K_CODES 1024
#define D_DIM   256
#define N_VEC   32768
#define BETA    0.25f
#define DECAY   0.99f
#define EPSV    1e-5f

// d_out layout (float32), offsets in elements
#define OFF_ZQ   0          // parks zf[n][d] (k_trans -> k_fix/k_dw2), overwritten by k_epi
#define OFF_IDX  8388608
#define OFF_LOSS 8421376
#define OFF_EMB  8421377
#define OFF_CS   8683521    // counts -> new_cs (k_scan, in place)
#define OFF_EMAW 8684545    // B_swz fp16 until k_zero; then dw accum -> new_ema_w

// ws layout (floats / ints)
#define WS_EMBT    0        // embT[d][j] fp32 (262144)
#define WS_ENORM   262144   // 1024
#define WS_ELOMAX  263168
#define WS_FIXCNT  263169
#define WS_FIXLIST 263424   // 32768 ints; reused as BUCKET by k_scatter/k_dw2
#define WS_OFF     296192   // 1024 ints
#define WS_POS     297216   // 1024 ints
#define WS_CNT     298240   // 1024 ints
#define WS_CHTAB   299264   // 2048 ints
#define WS_TC      301312   // 1 int      (total ~1.18 MB)

#define CHUNK 32

typedef _Float16 f16;
typedef f16   f16x8 __attribute__((ext_vector_type(8)));
typedef float f32x4 __attribute__((ext_vector_type(4)));

__device__ inline void top2_fold(float v, int j, float& d1, int& j1, float& d2, int& j2) {
    if (v < d1 || (v == d1 && j < j1)) { d2 = d1; j2 = j1; d1 = v; j1 = j; }
    else if (v < d2 || (v == d2 && j < j2)) { d2 = v; j2 = j; }
}
__device__ inline void top2_merge(float& d1, int& j1, float& d2, int& j2,
                                  float od1, int oj1, float od2, int oj2) {
    if (od1 < d1 || (od1 == d1 && oj1 < j1)) {
        float nd2; int nj2;
        if (d1 < od2 || (d1 == od2 && j1 < oj2)) { nd2 = d1; nj2 = j1; }
        else { nd2 = od2; nj2 = oj2; }
        d2 = nd2; j2 = nj2; d1 = od1; j1 = oj1;
    } else {
        if (od1 < d2 || (od1 == d2 && oj1 < j2)) { d2 = od1; j2 = oj1; }
    }
}

// ---------------------------------------------------------------- init
__global__ void k_init(float* __restrict__ out, float* __restrict__ ws) {
    int i = threadIdx.x;                         // 1 block x 1024
    out[OFF_CS + i] = 0.f;
    if (i == 0) {
        out[OFF_LOSS] = 0.f;
        ws[WS_ELOMAX] = 0.f;
        *(int*)(ws + WS_FIXCNT) = 0;
    }
}

// ------------------------------------------------- embT + enorm + elomax
__global__ void k_prep(const float* __restrict__ emb, float* __restrict__ ws) {
    int j    = blockIdx.x * 4 + (threadIdx.x >> 6);   // 256 blocks
    int lane = threadIdx.x & 63;
    float4 v = reinterpret_cast<const float4*>(emb + j * D_DIM)[lane];
    ws[(lane * 4 + 0) * 1024 + j] = v.x;
    ws[(lane * 4 + 1) * 1024 + j] = v.y;
    ws[(lane * 4 + 2) * 1024 + j] = v.z;
    ws[(lane * 4 + 3) * 1024 + j] = v.w;
    float s = v.x * v.x + v.y * v.y + v.z * v.z + v.w * v.w;
    float lx = v.x - (float)(f16)v.x, ly = v.y - (float)(f16)v.y;
    float lz = v.z - (float)(f16)v.z, lw = v.w - (float)(f16)v.w;
    float sl = lx * lx + ly * ly + lz * lz + lw * lw;
    #pragma unroll
    for (int o = 32; o > 0; o >>= 1) { s += __shfl_xor(s, o, 64); sl += __shfl_xor(sl, o, 64); }
    if (lane == 0) {
        ws[WS_ENORM + j] = s;
        atomicMax((int*)(ws + WS_ELOMAX), __float_as_int(sqrtf(sl)));
    }
}

// ------------------------------------------------- B_swz (fp16 fragment order)
__global__ void k_prep_b(const float* __restrict__ emb, float* __restrict__ out) {
    int slot = blockIdx.x * 256 + threadIdx.x;   // 128 blocks -> 32768 slots
    int lane = slot & 63;
    int kbjt = slot >> 6;
    int kb   = kbjt & 7;
    int jt   = kbjt >> 3;
    int j    = jt * 16 + (lane & 15);
    int d0   = kb * 32 + (lane >> 4) * 8;
    float4 e0 = *reinterpret_cast<const float4*>(emb + j * D_DIM + d0);
    float4 e1 = *reinterpret_cast<const float4*>(emb + j * D_DIM + d0 + 4);
    f16x8 w;
    w[0] = (f16)e0.x; w[1] = (f16)e0.y; w[2] = (f16)e0.z; w[3] = (f16)e0.w;
    w[4] = (f16)e1.x; w[5] = (f16)e1.y; w[6] = (f16)e1.z; w[7] = (f16)e1.w;
    f16* dst = (f16*)(out + OFF_EMAW);
    *reinterpret_cast<f16x8*>(dst + slot * 8) = w;
}

// ------------------------------------------------- zf[n][d] row-major transpose
__global__ void k_trans(const float* __restrict__ z, float* __restrict__ out) {
    __shared__ float tile[32][33];
    int bid = blockIdx.x;                        // 8192 blocks
    int b   = bid >> 8;
    int rem = bid & 255;
    int d0  = (rem >> 5) * 32;
    int hw0 = (rem & 31) * 32;
    const int tid = threadIdx.x;                 // 256
    #pragma unroll
    for (int rep = 0; rep < 4; ++rep) {
        int elem = rep * 256 + tid;
        int dl = elem >> 5, hwl = elem & 31;
        tile[dl][hwl] = z[b * (D_DIM * 1024) + (d0 + dl) * 1024 + hw0 + hwl];
    }
    __syncthreads();
    #pragma unroll
    for (int rep = 0; rep < 4; ++rep) {
        int elem = rep * 256 + tid;
        int hwl = elem >> 5, dl = elem & 31;
        out[OFF_ZQ + (long)(b * 1024 + hw0 + hwl) * 256 + d0 + dl] = tile[dl][hwl];
    }
}

// ---------------------------------------------------------------- main (MFMA)
__global__ __launch_bounds__(512, 2)
void k_main(const float* __restrict__ z, float* __restrict__ ws,
            float* __restrict__ out) {
    __shared__ f16   zl[64][520];
    __shared__ float els[K_CODES];
    __shared__ float red[64][8][4];
    __shared__ float znl[64];

    const int tid  = threadIdx.x;     // 512
    const int lane = tid & 63;
    const int w    = tid >> 6;
    const int n0   = blockIdx.x * 64; // 512 blocks
    const int b    = n0 >> 10;
    const int hw0  = n0 & 1023;
    const float* zb = z + b * (D_DIM * 1024) + hw0;

    #pragma unroll
    for (int rep = 0; rep < 8; ++rep) {
        int flat = rep * 512 + tid;
        int d    = flat >> 4;
        int n4   = (flat & 15) * 4;
        float4 v = *reinterpret_cast<const float4*>(zb + d * 1024 + n4);
        float vv[4] = {v.x, v.y, v.z, v.w};
        #pragma unroll
        for (int c = 0; c < 4; ++c) {
            f16 hi = (f16)vv[c];
            f16 lo = (f16)(vv[c] - (float)hi);
            zl[n4 + c][d]       = hi;
            zl[n4 + c][256 + d] = lo;
        }
    }
    #pragma unroll
    for (int rep = 0; rep < 2; ++rep) {
        int j = rep * 512 + tid;
        els[j] = ws[WS_ENORM + j];
    }
    __syncthreads();

    if (tid < 64) {
        float s = 0.f;
        for (int d = 0; d < 256; ++d) {
            float q = (float)zl[tid][d] + (float)zl[tid][256 + d];
            s += q * q;
        }
        znl[tid] = s;
    }

    const f16* Bw = (const f16*)(out + OFF_EMAW);
    const int arow = lane & 15, aoff = (lane >> 4) * 8;
    const int jt0 = w * 8;
    f32x4 acc[4][8];
    #pragma unroll
    for (int i = 0; i < 4; ++i)
        #pragma unroll
        for (int q = 0; q < 8; ++q) acc[i][q] = (f32x4){0.f, 0.f, 0.f, 0.f};

    for (int kt = 0; kt < 16; ++kt) {
        int kb   = kt & 7;
        int koff = ((kt & 8) ? 256 : 0) + kb * 32 + aoff;
        f16x8 a[4];
        #pragma unroll
        for (int i = 0; i < 4; ++i)
            a[i] = *reinterpret_cast<const f16x8*>(&zl[i * 16 + arow][koff]);
        #pragma unroll
        for (int q = 0; q < 8; ++q) {
            f16x8 bq = *reinterpret_cast<const f16x8*>(
                Bw + (((jt0 + q) * 8 + kb) * 64 + lane) * 8);
            #pragma unroll
            for (int i = 0; i < 4; ++i)
                acc[i][q] = __builtin_amdgcn_mfma_f32_16x16x32_f16(a[i], bq, acc[i][q], 0, 0, 0);
        }
    }
    __syncthreads();

    #pragma unroll
    for (int i = 0; i < 4; ++i) {
        #pragma unroll
        for (int r = 0; r < 4; ++r) {
            float d1 = 3.4e38f, d2 = 3.4e38f; int j1 = -1, j2 = -1;
            #pragma unroll
            for (int q = 0; q < 8; ++q) {
                int j = (jt0 + q) * 16 + (lane & 15);
                float v = els[j] - 2.f * acc[i][q][r];
                top2_fold(v, j, d1, j1, d2, j2);
            }
            #pragma unroll
            for (int s = 1; s < 16; s <<= 1) {
                float od1 = __shfl_xor(d1, s, 64); int oj1 = __shfl_xor(j1, s, 64);
                float od2 = __shfl_xor(d2, s, 64); int oj2 = __shfl_xor(j2, s, 64);
                top2_merge(d1, j1, d2, j2, od1, oj1, od2, oj2);
            }
            if ((lane & 15) == 0) {
                int row = i * 16 + (lane >> 4) * 4 + r;
                red[row][w][0] = d1; red[row][w][1] = (float)j1;
                red[row][w][2] = d2; red[row][w][3] = (float)j2;
            }
        }
    }
    __syncthreads();

    if (tid < 64) {
        int row = tid;
        float d1 = red[row][0][0], d2 = red[row][0][2];
        int   j1 = (int)red[row][0][1], j2 = (int)red[row][0][3];
        #pragma unroll
        for (int ww = 1; ww < 8; ++ww)
            top2_merge(d1, j1, d2, j2, red[row][ww][0], (int)red[row][ww][1],
                       red[row][ww][2], (int)red[row][ww][3]);
        int n = n0 + row;
        out[OFF_IDX + n] = (float)j1;
        float margin = 4.f * sqrtf(znl[row]) * ws[WS_ELOMAX] + 0.05f;
        if (d2 - d1 <= margin) {
            int p = atomicAdd((int*)(ws + WS_FIXCNT), 1);
            ((int*)(ws + WS_FIXLIST))[p] = n;
        }
    }
}

// ---------------------------------------------------------------- exact recompute (batched 8 rows)
__global__ void k_fix(const float* __restrict__ ws_c, float* __restrict__ ws,
                      float* __restrict__ out) {
    __shared__ float zr[8][256];
    __shared__ float rd[8][4]; __shared__ int rj[8][4];
    const int tid = threadIdx.x;                 // 256
    const int cnt = *(const int*)(ws_c + WS_FIXCNT);
    const int* fixlist = (const int*)(ws_c + WS_FIXLIST);
    const int groups = (cnt + 7) >> 3;
    const float4 en = *reinterpret_cast<const float4*>(ws_c + WS_ENORM + tid * 4);

    for (int g = blockIdx.x; g < groups; g += gridDim.x) {
        int nrow[8];
        #pragma unroll
        for (int r = 0; r < 8; ++r) {
            int slot = g * 8 + r;
            nrow[r] = (slot < cnt) ? fixlist[slot] : -1;
        }
        #pragma unroll
        for (int r = 0; r < 8; ++r)
            zr[r][tid] = (nrow[r] >= 0) ? out[OFF_ZQ + (long)nrow[r] * 256 + tid] : 0.f;
        __syncthreads();

        float acc[8][4];
        #pragma unroll
        for (int r = 0; r < 8; ++r)
            #pragma unroll
            for (int q = 0; q < 4; ++q) acc[r][q] = 0.f;
        for (int d = 0; d < 256; ++d) {
            float4 e = *reinterpret_cast<const float4*>(ws_c + WS_EMBT + d * 1024 + tid * 4);
            #pragma unroll
            for (int r = 0; r < 8; ++r) {
                float zd = zr[r][d];
                acc[r][0] += zd * e.x; acc[r][1] += zd * e.y;
                acc[r][2] += zd * e.z; acc[r][3] += zd * e.w;
            }
        }
        #pragma unroll
        for (int r = 0; r < 8; ++r) {
            float best = 3.4e38f; int bj = 0;
            #pragma unroll
            for (int q = 0; q < 4; ++q) {
                int j = tid * 4 + q;
                float v = ((const float*)&en)[q] - 2.f * acc[r][q];
                if (v < best || (v == best && j < bj)) { best = v; bj = j; }
            }
            #pragma unroll
            for (int o = 1; o < 64; o <<= 1) {
                float ov = __shfl_xor(best, o, 64);
                int   oj = __shfl_xor(bj, o, 64);
                if (ov < best || (ov == best && oj < bj)) { best = ov; bj = oj; }
            }
            if ((tid & 63) == 0) { rd[r][tid >> 6] = best; rj[r][tid >> 6] = bj; }
        }
        __syncthreads();
        if (tid < 8) {
            int r = tid;
            float v = rd[r][0]; int j = rj[r][0];
            #pragma unroll
            for (int ww = 1; ww < 4; ++ww)
                if (rd[r][ww] < v || (rd[r][ww] == v && rj[r][ww] < j)) { v = rd[r][ww]; j = rj[r][ww]; }
            int slot = g * 8 + r;
            if (slot < cnt) out[OFF_IDX + fixlist[slot]] = (float)j;
        }
        __syncthreads();
    }
}

// ---------------------------------------------------------------- counts
__global__ void k_count(float* __restrict__ out) {
    int n = blockIdx.x * 256 + threadIdx.x;      // 128 blocks
    int j = (int)out[OFF_IDX + n];
    atomicAdd(out + OFF_CS + j, 1.0f);
}

// ---------------------------------------------------------------- scan: offsets + chunk table + new_cs
__global__ void k_scan(const float* __restrict__ ema_cs, float* __restrict__ ws,
                       float* __restrict__ out) {
    __shared__ float s[K_CODES];
    int tid = threadIdx.x;                       // 1024
    float cntf = out[OFF_CS + tid];
    int   cnt  = (int)cntf;
    float raw  = ema_cs[tid] * DECAY + 0.01f * cntf;

    // member-offset exclusive scan
    s[tid] = cntf;
    __syncthreads();
    for (int off = 1; off < 1024; off <<= 1) {
        float v = (tid >= off) ? s[tid - off] : 0.f;
        __syncthreads();
        s[tid] += v;
        __syncthreads();
    }
    int excl = (int)(s[tid] - cntf);
    ((int*)(ws + WS_OFF))[tid] = excl;
    ((int*)(ws + WS_POS))[tid] = excl;
    ((int*)(ws + WS_CNT))[tid] = cnt;
    __syncthreads();

    // chunk-offset exclusive scan + chunk table
    int nch = (cnt + CHUNK - 1) / CHUNK;
    s[tid] = (float)nch;
    __syncthreads();
    for (int off = 1; off < 1024; off <<= 1) {
        float v = (tid >= off) ? s[tid - off] : 0.f;
        __syncthreads();
        s[tid] += v;
        __syncthreads();
    }
    int chexcl = (int)s[tid] - nch;
    int* chtab = (int*)(ws + WS_CHTAB);
    for (int k = 0; k < nch; ++k)
        chtab[chexcl + k] = (tid << 16) | k;
    if (tid == 1023) *(int*)(ws + WS_TC) = chexcl + nch;
    __syncthreads();

    // new_cs (Laplace)
    s[tid] = raw;
    __syncthreads();
    for (int st = 512; st > 0; st >>= 1) {
        if (tid < st) s[tid] += s[tid + st];
        __syncthreads();
    }
    float ntot = s[0];
    out[OFF_CS + tid] = (raw + EPSV) / (ntot + K_CODES * EPSV) * ntot;
}

// ---------------------------------------------------------------- scatter into buckets
__global__ void k_scatter(const float* __restrict__ out_c, float* __restrict__ ws) {
    int n = blockIdx.x * 256 + threadIdx.x;      // 128 blocks
    int j = (int)out_c[OFF_IDX + n];
    int p = atomicAdd((int*)(ws + WS_POS) + j, 1);
    ((int*)(ws + WS_FIXLIST))[p] = n;            // bucket reuses fixlist slot
}

// ---------------------------------------------------------------- zero dw accumulator
__global__ void k_zero(float* __restrict__ out) {
    int i = blockIdx.x * 256 + threadIdx.x;      // 256 blocks
    *reinterpret_cast<float4*>(out + OFF_EMAW + i * 4) =
        (float4){0.f, 0.f, 0.f, 0.f};
}

// ---------------------------------------------------------------- dw partial sums (chunked, balanced)
__global__ void k_dw2(const float* __restrict__ ws, float* __restrict__ out) {
    __shared__ int midx[CHUNK];
    const int b = blockIdx.x;                    // 2048 blocks
    if (b >= *(const int*)(ws + WS_TC)) return;
    const int tab = ((const int*)(ws + WS_CHTAB))[b];
    const int j   = tab >> 16;
    const int lc  = tab & 0xffff;
    const int off = ((const int*)(ws + WS_OFF))[j];
    const int cnt = ((const int*)(ws + WS_CNT))[j];
    const int base = lc * CHUNK;
    const int m    = min(CHUNK, cnt - base);
    const int tid  = threadIdx.x;                // 256: d = tid
    if (tid < CHUNK)
        midx[tid] = (tid < m) ? ((const int*)(ws + WS_FIXLIST))[off + base + tid] : 0;
    __syncthreads();
    float acc = 0.f;
    for (int i = 0; i < m; ++i)
        acc += out[OFF_ZQ + (long)midx[i] * 256 + tid];
    atomicAdd(out + OFF_EMAW + j * 256 + tid, acc);
}

// ---------------------------------------------------------------- new_ema_w + new_embedding
__global__ void k_emb2(const float* __restrict__ ema_w, float* __restrict__ out) {
    int i4 = blockIdx.x * 256 + threadIdx.x;     // 256 blocks -> 65536 float4
    int j  = i4 >> 6;
    float4 dw = *reinterpret_cast<float4*>(out + OFF_EMAW + i4 * 4);
    float4 ew = *reinterpret_cast<const float4*>(ema_w + i4 * 4);
    float inv = 1.f / out[OFF_CS + j];
    float4 nw = {ew.x * DECAY + 0.01f * dw.x, ew.y * DECAY + 0.01f * dw.y,
                 ew.z * DECAY + 0.01f * dw.z, ew.w * DECAY + 0.01f * dw.w};
    *reinterpret_cast<float4*>(out + OFF_EMAW + i4 * 4) = nw;
    float4 nb = {nw.x * inv, nw.y * inv, nw.z * inv, nw.w * inv};
    *reinterpret_cast<float4*>(out + OFF_EMB + i4 * 4) = nb;
}

// ---------------------------------------------------------------- z_q + loss
__global__ void k_epi(const float* __restrict__ z, const float* __restrict__ emb,
                      float* __restrict__ out) {
    __shared__ float erows[32][257];
    __shared__ int js[32];
    const int tid = threadIdx.x;                 // 256
    const int n0  = blockIdx.x * 32;             // 1024 blocks
    const int b   = n0 >> 10;
    const int hw0 = n0 & 1023;
    if (tid < 32) js[tid] = (int)out[OFF_IDX + n0 + tid];
    __syncthreads();
    #pragma unroll 4
    for (int r = 0; r < 32; ++r)
        erows[r][tid] = emb[js[r] * D_DIM + tid];
    __syncthreads();
    const long zqb = (long)b * (D_DIM * 1024) + hw0;
    float ls = 0.f;
    #pragma unroll 4
    for (int rep = 0; rep < 32; ++rep) {
        int elem = rep * 256 + tid;
        int d    = elem >> 5;
        int nl   = elem & 31;
        float zq = erows[nl][d];
        float zv = z[zqb + d * 1024 + nl];
        out[OFF_ZQ + zqb + d * 1024 + nl] = zq;
        float df = zq - zv; ls += df * df;
    }
    #pragma unroll
    for (int o = 32; o > 0; o >>= 1) ls += __shfl_xor(ls, o, 64);
    if ((tid & 63) == 0)
        atomicAdd(out + OFF_LOSS, ls * (BETA / (float)(N_VEC * D_DIM)));
}

// ---------------------------------------------------------------- launch
extern "C" void kernel_launch(void* const* d_in, const int* in_sizes, int n_in,
                              void* d_out, int out_size, void* d_ws, size_t ws_size,
                              hipStream_t stream) {
    const float* z      = (const float*)d_in[0];
    const float* emb    = (const float*)d_in[1];
    const float* ema_cs = (const float*)d_in[2];
    const float* ema_w  = (const float*)d_in[3];
    float* out = (float*)d_out;
    float* ws  = (float*)d_ws;                   // ~1.18 MB used

    hipLaunchKernelGGL(k_init,    dim3(1),    dim3(1024), 0, stream, out, ws);
    hipLaunchKernelGGL(k_prep,    dim3(256),  dim3(256),  0, stream, emb, ws);
    hipLaunchKernelGGL(k_prep_b,  dim3(128),  dim3(256),  0, stream, emb, out);
    hipLaunchKernelGGL(k_trans,   dim3(8192), dim3(256),  0, stream, z, out);
    hipLaunchKernelGGL(k_main,    dim3(512),  dim3(512),  0, stream, z, ws, out);
    hipLaunchKernelGGL(k_fix,     dim3(256),  dim3(256),  0, stream, ws, ws, out);
    hipLaunchKernelGGL(k_count,   dim3(128),  dim3(256),  0, stream, out);
    hipLaunchKernelGGL(k_scan,    dim3(1),    dim3(1024), 0, stream, ema_cs, ws, out);
    hipLaunchKernelGGL(k_scatter, dim3(128),  dim3(256),  0, stream, out, ws);
    hipLaunchKernelGGL(k_zero,    dim3(256),  dim3(256),  0, stream, out);
    hipLaunchKernelGGL(k_dw2,     dim3(2048), dim3(256),  0, stream, ws, out);
    hipLaunchKernelGGL(k_emb2,    dim3(256),  dim3(256),  0, stream, ema_w, out);
    hipLaunchKernelGGL(k_epi,     dim3(1024), dim3(256),  0, stream, z, emb, out);
}

// Round 8
// 425.652 us; speedup vs baseline: 7.8592x; 1.0180x over previous
//
#include <hip/hip_runtime.h>

#define K_CODES 1024
#define D_DIM   256
#define N_VEC   32768
#define BETA    0.25f
#define DECAY   0.99f
#define EPSV    1e-5f

// d_out layout (float32), offsets in elements
#define OFF_ZQ   0          // parks zf[n][d] (k_trans -> k_main/k_fix/k_dw2), overwritten by k_epi
#define OFF_IDX  8388608
#define OFF_LOSS 8421376
#define OFF_EMB  8421377
#define OFF_CS   8683521    // counts -> new_cs (k_scan, in place)
#define OFF_EMAW 8684545    // B_swz fp16 (at +3 for 16B align) until k_zero; then dw -> new_ema_w

// ws layout (floats / ints), ~5.7 MB
#define WS_EMBT    0        // embT[d][j] fp32
#define WS_ENORM   262144   // 1024
#define WS_ELOMAX  263168
#define WS_EHIMAX  263169
#define WS_FIXCNT  263170
#define WS_S2      263172   // 32768 rows x 8 jc x float4 = 1048576 floats (16B-aligned)
#define WS_ZN2     1311748  // 32768
#define WS_ZLO2    1344516  // 32768 (contiguous after ZN2)
#define WS_FIXLIST 1377284  // 32768 ints; reused as BUCKET
#define WS_OFF     1410052
#define WS_POS     1411076
#define WS_CNT     1412100
#define WS_CHTAB   1413124  // 2048
#define WS_TC      1415172

#define CHUNK 32
#define ZL_LD 264           // f16 row stride: 528B -> 2-way max on b128 reads

typedef _Float16 f16;
typedef f16   f16x4 __attribute__((ext_vector_type(4)));
typedef f16   f16x8 __attribute__((ext_vector_type(8)));
typedef float f32x4 __attribute__((ext_vector_type(4)));

__device__ inline void top2_fold(float v, int j, float& d1, int& j1, float& d2, int& j2) {
    if (v < d1 || (v == d1 && j < j1)) { d2 = d1; j2 = j1; d1 = v; j1 = j; }
    else if (v < d2 || (v == d2 && j < j2)) { d2 = v; j2 = j; }
}
__device__ inline void top2_merge(float& d1, int& j1, float& d2, int& j2,
                                  float od1, int oj1, float od2, int oj2) {
    if (od1 < d1 || (od1 == d1 && oj1 < j1)) {
        float nd2; int nj2;
        if (d1 < od2 || (d1 == od2 && j1 < oj2)) { nd2 = d1; nj2 = j1; }
        else { nd2 = od2; nj2 = oj2; }
        d2 = nd2; j2 = nj2; d1 = od1; j1 = oj1;
    } else {
        if (od1 < d2 || (od1 == d2 && oj1 < j2)) { d2 = od1; j2 = oj1; }
    }
}

// ---------------------------------------------------------------- init
__global__ void k_init(float* __restrict__ out, float* __restrict__ ws) {
    int i = blockIdx.x * 1024 + threadIdx.x;     // 64 blocks x 1024 = 65536
    ws[WS_ZN2 + i] = 0.f;                        // covers ZN2 + ZLO2 (contiguous)
    if (i < K_CODES) out[OFF_CS + i] = 0.f;
    if (i == 0) {
        out[OFF_LOSS] = 0.f;
        ws[WS_ELOMAX] = 0.f;
        ws[WS_EHIMAX] = 0.f;
        *(int*)(ws + WS_FIXCNT) = 0;
    }
}

// ------------------------------------------------- embT + enorm + elomax/ehimax
__global__ void k_prep(const float* __restrict__ emb, float* __restrict__ ws) {
    int j    = blockIdx.x * 4 + (threadIdx.x >> 6);   // 256 blocks
    int lane = threadIdx.x & 63;
    float4 v = reinterpret_cast<const float4*>(emb + j * D_DIM)[lane];
    ws[(lane * 4 + 0) * 1024 + j] = v.x;
    ws[(lane * 4 + 1) * 1024 + j] = v.y;
    ws[(lane * 4 + 2) * 1024 + j] = v.z;
    ws[(lane * 4 + 3) * 1024 + j] = v.w;
    float s = v.x * v.x + v.y * v.y + v.z * v.z + v.w * v.w;
    float hx = (float)(f16)v.x, hy = (float)(f16)v.y;
    float hz = (float)(f16)v.z, hw = (float)(f16)v.w;
    float lx = v.x - hx, ly = v.y - hy, lz = v.z - hz, lw = v.w - hw;
    float sl = lx * lx + ly * ly + lz * lz + lw * lw;
    float sh = hx * hx + hy * hy + hz * hz + hw * hw;
    #pragma unroll
    for (int o = 32; o > 0; o >>= 1) {
        s  += __shfl_xor(s,  o, 64);
        sl += __shfl_xor(sl, o, 64);
        sh += __shfl_xor(sh, o, 64);
    }
    if (lane == 0) {
        ws[WS_ENORM + j] = s;
        atomicMax((int*)(ws + WS_ELOMAX), __float_as_int(sqrtf(sl)));
        atomicMax((int*)(ws + WS_EHIMAX), __float_as_int(sqrtf(sh)));
    }
}

// ------------------------------------------------- B_swz (fp16 fragment order, 16B-aligned base)
__global__ void k_prep_b(const float* __restrict__ emb, float* __restrict__ out) {
    int slot = blockIdx.x * 256 + threadIdx.x;   // 128 blocks -> 32768 slots
    int lane = slot & 63;
    int kbjt = slot >> 6;
    int kb   = kbjt & 7;                         // k-block of 32 (K=256)
    int jt   = kbjt >> 3;                        // j-tile of 16
    int j    = jt * 16 + (lane & 15);
    int d0   = kb * 32 + (lane >> 4) * 8;
    float4 e0 = *reinterpret_cast<const float4*>(emb + j * D_DIM + d0);
    float4 e1 = *reinterpret_cast<const float4*>(emb + j * D_DIM + d0 + 4);
    f16x8 w;
    w[0] = (f16)e0.x; w[1] = (f16)e0.y; w[2] = (f16)e0.z; w[3] = (f16)e0.w;
    w[4] = (f16)e1.x; w[5] = (f16)e1.y; w[6] = (f16)e1.z; w[7] = (f16)e1.w;
    f16* dst = (f16*)(out + OFF_EMAW + 3);       // +3 floats -> 16B aligned
    *reinterpret_cast<f16x8*>(dst + slot * 8) = w;
}

// ------------------------------------------------- zf[n][d] transpose + row norms
__global__ void k_trans(const float* __restrict__ z, float* __restrict__ out,
                        float* __restrict__ ws) {
    __shared__ float tile[32][33];
    int bid = blockIdx.x;                        // 8192 blocks
    int b   = bid >> 8;
    int rem = bid & 255;
    int d0  = (rem >> 5) * 32;
    int hw0 = (rem & 31) * 32;
    const int tid = threadIdx.x;                 // 256
    #pragma unroll
    for (int rep = 0; rep < 4; ++rep) {
        int elem = rep * 256 + tid;
        int dl = elem >> 5, hwl = elem & 31;
        tile[dl][hwl] = z[b * (D_DIM * 1024) + (d0 + dl) * 1024 + hw0 + hwl];
    }
    __syncthreads();
    #pragma unroll
    for (int rep = 0; rep < 4; ++rep) {
        int elem = rep * 256 + tid;
        int hwl = elem >> 5, dl = elem & 31;
        out[OFF_ZQ + (long)(b * 1024 + hw0 + hwl) * 256 + d0 + dl] = tile[dl][hwl];
    }
    if (tid < 32) {
        float sn = 0.f, sl = 0.f;
        #pragma unroll 8
        for (int dl = 0; dl < 32; ++dl) {
            float v  = tile[dl][tid];
            float lo = v - (float)(f16)v;
            sn += v * v; sl += lo * lo;
        }
        int n = b * 1024 + hw0 + tid;
        atomicAdd(ws + WS_ZN2 + n, sn);
        atomicAdd(ws + WS_ZLO2 + n, sl);
    }
}

// ---------------------------------------------------------------- main (MFMA, j-split)
__global__ __launch_bounds__(256, 4)
void k_main(float* __restrict__ out, float* __restrict__ ws) {
    __shared__ f16   zl[64][ZL_LD];   // 33.8 KB
    __shared__ float els_s[128];

    const int tid  = threadIdx.x;     // 256 = 4 waves
    const int lane = tid & 63;
    const int w    = tid >> 6;
    const int bid  = blockIdx.x;      // 4096 = 512 rowtiles x 8 jc
    const int rt   = bid & 511;       // consecutive bids -> consecutive rt (XCD = rt%8 fixed)
    const int jc   = bid >> 9;
    const int n0   = rt * 64;
    const float* zf = out + OFF_ZQ;

    // ---- stage zf rows -> f16 hi (coalesced rows, contiguous 8B LDS writes)
    #pragma unroll
    for (int rep = 0; rep < 16; ++rep) {
        int flat = rep * 256 + tid;              // 0..4095 quads
        int row  = flat >> 6;
        int dq   = (flat & 63) * 4;
        float4 v = *reinterpret_cast<const float4*>(zf + (long)(n0 + row) * 256 + dq);
        f16x4 h = {(f16)v.x, (f16)v.y, (f16)v.z, (f16)v.w};
        *reinterpret_cast<f16x4*>(&zl[row][dq]) = h;
    }
    if (tid < 128) els_s[tid] = ws[WS_ENORM + jc * 128 + tid];
    __syncthreads();

    // ---- MFMA k-loop: K=256 hi-only
    const f16* Bj = (const f16*)(out + OFF_EMAW + 3) + (size_t)jc * 32768 + lane * 8;
    const int arow = w * 16 + (lane & 15);
    const int aoff = (lane >> 4) * 8;
    f32x4 acc[8];
    #pragma unroll
    for (int q = 0; q < 8; ++q) acc[q] = (f32x4){0.f, 0.f, 0.f, 0.f};

    #pragma unroll
    for (int kb = 0; kb < 8; ++kb) {
        f16x8 a = *reinterpret_cast<const f16x8*>(&zl[arow][kb * 32 + aoff]);
        #pragma unroll
        for (int q = 0; q < 8; ++q) {
            f16x8 bq = *reinterpret_cast<const f16x8*>(Bj + q * 4096 + kb * 512);
            acc[q] = __builtin_amdgcn_mfma_f32_16x16x32_f16(a, bq, acc[q], 0, 0, 0);
        }
    }

    // ---- per-row top-2 over this block's 128 j -> S2
    #pragma unroll
    for (int r = 0; r < 4; ++r) {
        float d1 = 3.4e38f, d2 = 3.4e38f; int j1 = -1, j2 = -1;
        #pragma unroll
        for (int q = 0; q < 8; ++q) {
            int jl = q * 16 + (lane & 15);
            float v = els_s[jl] - 2.f * acc[q][r];
            top2_fold(v, jc * 128 + jl, d1, j1, d2, j2);
        }
        #pragma unroll
        for (int s = 1; s < 16; s <<= 1) {
            float od1 = __shfl_xor(d1, s, 64); int oj1 = __shfl_xor(j1, s, 64);
            float od2 = __shfl_xor(d2, s, 64); int oj2 = __shfl_xor(j2, s, 64);
            top2_merge(d1, j1, d2, j2, od1, oj1, od2, oj2);
        }
        if ((lane & 15) == 0) {
            int row = n0 + w * 16 + (lane >> 4) * 4 + r;
            *reinterpret_cast<float4*>(ws + WS_S2 + ((size_t)row * 8 + jc) * 4) =
                (float4){d1, (float)j1, d2, (float)j2};
        }
    }
}

// ---------------------------------------------------------------- global top-2 merge + flag
__global__ void k_merge(float* __restrict__ ws, float* __restrict__ out) {
    int n = blockIdx.x * 256 + threadIdx.x;      // 128 blocks
    const float4* S2 = reinterpret_cast<const float4*>(ws + WS_S2) + (size_t)n * 8;
    float4 e0 = S2[0];
    float d1 = e0.x; int j1 = (int)e0.y; float d2 = e0.z; int j2 = (int)e0.w;
    #pragma unroll
    for (int c = 1; c < 8; ++c) {
        float4 e = S2[c];
        top2_merge(d1, j1, d2, j2, e.x, (int)e.y, e.z, (int)e.w);
    }
    out[OFF_IDX + n] = (float)j1;
    float margin = 4.f * (sqrtf(ws[WS_ZLO2 + n]) * ws[WS_EHIMAX] +
                          sqrtf(ws[WS_ZN2 + n])  * ws[WS_ELOMAX]) + 0.05f;
    if (d2 - d1 <= margin) {
        int p = atomicAdd((int*)(ws + WS_FIXCNT), 1);
        ((int*)(ws + WS_FIXLIST))[p] = n;
    }
}

// ---------------------------------------------------------------- exact recompute (batched 8 rows)
__global__ void k_fix(const float* __restrict__ ws_c, float* __restrict__ out) {
    __shared__ float zr[8][256];
    __shared__ float rd[8][4]; __shared__ int rj[8][4];
    const int tid = threadIdx.x;                 // 256
    const int cnt = *(const int*)(ws_c + WS_FIXCNT);
    const int* fixlist = (const int*)(ws_c + WS_FIXLIST);
    const int groups = (cnt + 7) >> 3;
    const float4 en = *reinterpret_cast<const float4*>(ws_c + WS_ENORM + tid * 4);

    for (int g = blockIdx.x; g < groups; g += gridDim.x) {
        int nrow[8];
        #pragma unroll
        for (int r = 0; r < 8; ++r) {
            int slot = g * 8 + r;
            nrow[r] = (slot < cnt) ? fixlist[slot] : -1;
        }
        #pragma unroll
        for (int r = 0; r < 8; ++r)
            zr[r][tid] = (nrow[r] >= 0) ? out[OFF_ZQ + (long)nrow[r] * 256 + tid] : 0.f;
        __syncthreads();

        float acc[8][4];
        #pragma unroll
        for (int r = 0; r < 8; ++r)
            #pragma unroll
            for (int q = 0; q < 4; ++q) acc[r][q] = 0.f;
        for (int d = 0; d < 256; ++d) {
            float4 e = *reinterpret_cast<const float4*>(ws_c + WS_EMBT + d * 1024 + tid * 4);
            #pragma unroll
            for (int r = 0; r < 8; ++r) {
                float zd = zr[r][d];
                acc[r][0] += zd * e.x; acc[r][1] += zd * e.y;
                acc[r][2] += zd * e.z; acc[r][3] += zd * e.w;
            }
        }
        #pragma unroll
        for (int r = 0; r < 8; ++r) {
            float best = 3.4e38f; int bj = 0;
            #pragma unroll
            for (int q = 0; q < 4; ++q) {
                int j = tid * 4 + q;
                float v = ((const float*)&en)[q] - 2.f * acc[r][q];
                if (v < best || (v == best && j < bj)) { best = v; bj = j; }
            }
            #pragma unroll
            for (int o = 1; o < 64; o <<= 1) {
                float ov = __shfl_xor(best, o, 64);
                int   oj = __shfl_xor(bj, o, 64);
                if (ov < best || (ov == best && oj < bj)) { best = ov; bj = oj; }
            }
            if ((tid & 63) == 0) { rd[r][tid >> 6] = best; rj[r][tid >> 6] = bj; }
        }
        __syncthreads();
        if (tid < 8) {
            int r = tid;
            float v = rd[r][0]; int j = rj[r][0];
            #pragma unroll
            for (int ww = 1; ww < 4; ++ww)
                if (rd[r][ww] < v || (rd[r][ww] == v && rj[r][ww] < j)) { v = rd[r][ww]; j = rj[r][ww]; }
            int slot = g * 8 + r;
            if (slot < cnt) out[OFF_IDX + fixlist[slot]] = (float)j;
        }
        __syncthreads();
    }
}

// ---------------------------------------------------------------- counts
__global__ void k_count(float* __restrict__ out) {
    int n = blockIdx.x * 256 + threadIdx.x;      // 128 blocks
    int j = (int)out[OFF_IDX + n];
    atomicAdd(out + OFF_CS + j, 1.0f);
}

// ---------------------------------------------------------------- scan: offsets + chunk table + new_cs
__global__ void k_scan(const float* __restrict__ ema_cs, float* __restrict__ ws,
                       float* __restrict__ out) {
    __shared__ float s[K_CODES];
    int tid = threadIdx.x;                       // 1024
    float cntf = out[OFF_CS + tid];
    int   cnt  = (int)cntf;
    float raw  = ema_cs[tid] * DECAY + 0.01f * cntf;

    s[tid] = cntf;
    __syncthreads();
    for (int off = 1; off < 1024; off <<= 1) {
        float v = (tid >= off) ? s[tid - off] : 0.f;
        __syncthreads();
        s[tid] += v;
        __syncthreads();
    }
    int excl = (int)(s[tid] - cntf);
    ((int*)(ws + WS_OFF))[tid] = excl;
    ((int*)(ws + WS_POS))[tid] = excl;
    ((int*)(ws + WS_CNT))[tid] = cnt;
    __syncthreads();

    int nch = (cnt + CHUNK - 1) / CHUNK;
    s[tid] = (float)nch;
    __syncthreads();
    for (int off = 1; off < 1024; off <<= 1) {
        float v = (tid >= off) ? s[tid - off] : 0.f;
        __syncthreads();
        s[tid] += v;
        __syncthreads();
    }
    int chexcl = (int)s[tid] - nch;
    int* chtab = (int*)(ws + WS_CHTAB);
    for (int k = 0; k < nch; ++k)
        chtab[chexcl + k] = (tid << 16) | k;
    if (tid == 1023) *(int*)(ws + WS_TC) = chexcl + nch;
    __syncthreads();

    s[tid] = raw;
    __syncthreads();
    for (int st = 512; st > 0; st >>= 1) {
        if (tid < st) s[tid] += s[tid + st];
        __syncthreads();
    }
    float ntot = s[0];
    out[OFF_CS + tid] = (raw + EPSV) / (ntot + K_CODES * EPSV) * ntot;
}

// ---------------------------------------------------------------- scatter into buckets
__global__ void k_scatter(const float* __restrict__ out_c, float* __restrict__ ws) {
    int n = blockIdx.x * 256 + threadIdx.x;      // 128 blocks
    int j = (int)out_c[OFF_IDX + n];
    int p = atomicAdd((int*)(ws + WS_POS) + j, 1);
    ((int*)(ws + WS_FIXLIST))[p] = n;
}

// ---------------------------------------------------------------- zero dw accumulator
__global__ void k_zero(float* __restrict__ out) {
    int i = blockIdx.x * 256 + threadIdx.x;      // 256 blocks
    *reinterpret_cast<float4*>(out + OFF_EMAW + i * 4) = (float4){0.f, 0.f, 0.f, 0.f};
}

// ---------------------------------------------------------------- dw partial sums (chunked)
__global__ void k_dw2(const float* __restrict__ ws, float* __restrict__ out) {
    __shared__ int midx[CHUNK];
    const int b = blockIdx.x;                    // 2048 blocks
    if (b >= *(const int*)(ws + WS_TC)) return;
    const int tab = ((const int*)(ws + WS_CHTAB))[b];
    const int j   = tab >> 16;
    const int lc  = tab & 0xffff;
    const int off = ((const int*)(ws + WS_OFF))[j];
    const int cnt = ((const int*)(ws + WS_CNT))[j];
    const int base = lc * CHUNK;
    const int m    = min(CHUNK, cnt - base);
    const int tid  = threadIdx.x;                // 256: d = tid
    if (tid < CHUNK)
        midx[tid] = (tid < m) ? ((const int*)(ws + WS_FIXLIST))[off + base + tid] : 0;
    __syncthreads();
    float acc = 0.f;
    for (int i = 0; i < m; ++i)
        acc += out[OFF_ZQ + (long)midx[i] * 256 + tid];
    atomicAdd(out + OFF_EMAW + j * 256 + tid, acc);
}

// ---------------------------------------------------------------- new_ema_w + new_embedding
__global__ void k_emb2(const float* __restrict__ ema_w, float* __restrict__ out) {
    int i4 = blockIdx.x * 256 + threadIdx.x;     // 256 blocks -> 65536 float4
    int j  = i4 >> 6;
    float4 dw = *reinterpret_cast<float4*>(out + OFF_EMAW + i4 * 4);
    float4 ew = *reinterpret_cast<const float4*>(ema_w + i4 * 4);
    float inv = 1.f / out[OFF_CS + j];
    float4 nw = {ew.x * DECAY + 0.01f * dw.x, ew.y * DECAY + 0.01f * dw.y,
                 ew.z * DECAY + 0.01f * dw.z, ew.w * DECAY + 0.01f * dw.w};
    *reinterpret_cast<float4*>(out + OFF_EMAW + i4 * 4) = nw;
    float4 nb = {nw.x * inv, nw.y * inv, nw.z * inv, nw.w * inv};
    *reinterpret_cast<float4*>(out + OFF_EMB + i4 * 4) = nb;
}

// ---------------------------------------------------------------- z_q + loss
__global__ void k_epi(const float* __restrict__ z, const float* __restrict__ emb,
                      float* __restrict__ out) {
    __shared__ float erows[32][257];
    __shared__ int js[32];
    const int tid = threadIdx.x;                 // 256
    const int n0  = blockIdx.x * 32;             // 1024 blocks
    const int b   = n0 >> 10;
    const int hw0 = n0 & 1023;
    if (tid < 32) js[tid] = (int)out[OFF_IDX + n0 + tid];
    __syncthreads();
    #pragma unroll 4
    for (int r = 0; r < 32; ++r)
        erows[r][tid] = emb[js[r] * D_DIM + tid];
    __syncthreads();
    const long zqb = (long)b * (D_DIM * 1024) + hw0;
    float ls = 0.f;
    #pragma unroll 4
    for (int rep = 0; rep < 32; ++rep) {
        int elem = rep * 256 + tid;
        int d    = elem >> 5;
        int nl   = elem & 31;
        float zq = erows[nl][d];
        float zv = z[zqb + d * 1024 + nl];
        out[OFF_ZQ + zqb + d * 1024 + nl] = zq;
        float df = zq - zv; ls += df * df;
    }
    #pragma unroll
    for (int o = 32; o > 0; o >>= 1) ls += __shfl_xor(ls, o, 64);
    if ((tid & 63) == 0)
        atomicAdd(out + OFF_LOSS, ls * (BETA / (float)(N_VEC * D_DIM)));
}

// ---------------------------------------------------------------- launch
extern "C" void kernel_launch(void* const* d_in, const int* in_sizes, int n_in,
                              void* d_out, int out_size, void* d_ws, size_t ws_size,
                              hipStream_t stream) {
    const float* z      = (const float*)d_in[0];
    const float* emb    = (const float*)d_in[1];
    const float* ema_cs = (const float*)d_in[2];
    const float* ema_w  = (const float*)d_in[3];
    float* out = (float*)d_out;
    float* ws  = (float*)d_ws;                   // ~5.7 MB used

    hipLaunchKernelGGL(k_init,    dim3(64),   dim3(1024), 0, stream, out, ws);
    hipLaunchKernelGGL(k_prep,    dim3(256),  dim3(256),  0, stream, emb, ws);
    hipLaunchKernelGGL(k_prep_b,  dim3(128),  dim3(256),  0, stream, emb, out);
    hipLaunchKernelGGL(k_trans,   dim3(8192), dim3(256),  0, stream, z, out, ws);
    hipLaunchKernelGGL(k_main,    dim3(4096), dim3(256),  0, stream, out, ws);
    hipLaunchKernelGGL(k_merge,   dim3(128),  dim3(256),  0, stream, ws, out);
    hipLaunchKernelGGL(k_fix,     dim3(256),  dim3(256),  0, stream, ws, out);
    hipLaunchKernelGGL(k_count,   dim3(128),  dim3(256),  0, stream, out);
    hipLaunchKernelGGL(k_scan,    dim3(1),    dim3(1024), 0, stream, ema_cs, ws, out);
    hipLaunchKernelGGL(k_scatter, dim3(128),  dim3(256),  0, stream, out, ws);
    hipLaunchKernelGGL(k_zero,    dim3(256),  dim3(256),  0, stream, out);
    hipLaunchKernelGGL(k_dw2,     dim3(2048), dim3(256),  0, stream, ws, out);
    hipLaunchKernelGGL(k_emb2,    dim3(256),  dim3(256),  0, stream, ema_w, out);
    hipLaunchKernelGGL(k_epi,     dim3(1024), dim3(256),  0, stream, z, emb, out);
}